// Round 16
// baseline (90.004 us; speedup 1.0000x reference)
//
#include <hip/hip_runtime.h>
#include <hip/hip_bf16.h>

// Problem constants (fixed by reference)
#define B_    4
#define Qn_   2048
#define S_    21760   // 128*128 + 64*64 + 32*32 + 16*16

typedef short  bfx4    __attribute__((ext_vector_type(4)));
typedef short  short8  __attribute__((ext_vector_type(8)));
typedef float  floatx4 __attribute__((ext_vector_type(4)));

__device__ __forceinline__ unsigned short f2bf(float f) {
    unsigned int u = __builtin_bit_cast(unsigned int, f);
    u += 0x7fffu + ((u >> 16) & 1u);   // round-to-nearest-even
    return (unsigned short)(u >> 16);
}
__device__ __forceinline__ float bf2f(unsigned short h) {
    unsigned int u = ((unsigned int)h) << 16;
    return __builtin_bit_cast(float, u);
}

// packed f32x8 -> bf16x8 via v_cvt_pk_bf16_f32 (RNE, 1 instr / 2 elems)
__device__ __forceinline__ short8 cvt_pk8(floatx4 f0, floatx4 f1) {
    union { unsigned int u[4]; short8 s; } r;
    asm("v_cvt_pk_bf16_f32 %0, %1, %2" : "=v"(r.u[0]) : "v"(f0[0]), "v"(f0[1]));
    asm("v_cvt_pk_bf16_f32 %0, %1, %2" : "=v"(r.u[1]) : "v"(f0[2]), "v"(f0[3]));
    asm("v_cvt_pk_bf16_f32 %0, %1, %2" : "=v"(r.u[2]) : "v"(f1[0]), "v"(f1[1]));
    asm("v_cvt_pk_bf16_f32 %0, %1, %2" : "=v"(r.u[3]) : "v"(f1[2]), "v"(f1[3]));
    return r.s;
}

// async global->LDS, 16B per lane. lds must be WAVE-UNIFORM base (lane*16 implicit).
__device__ __forceinline__ void async16(void* lds, const void* g) {
    __builtin_amdgcn_global_load_lds(
        (const __attribute__((address_space(1))) unsigned int*)g,
        (__attribute__((address_space(3))) unsigned int*)lds, 16, 0, 0);
}

template<int N>
__device__ __forceinline__ void wait_vm_lgkm0() {
    asm volatile("s_waitcnt vmcnt(%0) lgkmcnt(0)" :: "n"(N) : "memory");
}

// ---------------------------------------------------------------------------
// prep_all: ONE dispatch for all weight prep (r15 verified).
// ---------------------------------------------------------------------------
__global__ __launch_bounds__(1024) void prep_all(
        const float* __restrict__ Wv, const float* __restrict__ Wo,
        const float* __restrict__ Woff, const float* __restrict__ Wattn,
        const float* __restrict__ boff, const float* __restrict__ battn,
        short* __restrict__ Wvt, short* __restrict__ Wcat,
        short* __restrict__ Wof, float* __restrict__ bcat) {
    const int bid = blockIdx.x;
    const int t   = threadIdx.x;
    if (bid < 256) {
        const int k = bid;
        if (t < 256) {
            Wvt[t * 256 + k] = (short)f2bf(Wv[k * 256 + t]);
        } else if (t < 640) {
            const int n = t - 256;     // 0..383
            const float w = (n < 256) ? Woff[k * 256 + n] : Wattn[k * 128 + (n - 256)];
            Wcat[n * 256 + k] = (short)f2bf(w);
        }
        if (bid == 0 && t < 384)
            bcat[t] = (t < 256) ? boff[t] : battn[t - 256];
    } else {
        const int g = (bid - 256) * 1024 + t;   // 0..65535
        const int j  = g & 7;
        const int l  = (g >> 3) & 63;
        const int nf = (g >> 9) & 15;
        const int kc = g >> 13;
        const int k = kc * 32 + (l >> 4) * 8 + j;
        const int n = nf * 16 + (l & 15);
        Wof[g] = (short)f2bf(Wo[k * 256 + n]);
    }
}

// ---------------------------------------------------------------------------
// gemm_core: v8 inner structure, NF=2 (BN=128) for 24KB LDS -> 6 blocks/CU.
//   BM=64 rows, 4 waves (wave w: cols w*32 .. +31).  A f32 reg+cvt_pk staged;
//   B bf16 NxK via global_load_lds; 2-phase K-loop, counted vmcnt(2).
//   T5: s_setprio(1) around the MFMA cluster (independent blocks per CU ->
//   role diversity).  Swapped MFMA -> row-major stores.
// ---------------------------------------------------------------------------
template<int OUT_F32>
__device__ __forceinline__ void gemm_core(
        const float* __restrict__ Av, const short* __restrict__ Bt,
        const float* __restrict__ bias, void* __restrict__ Cv,
        long row0, int Ntot, int colbase,
        short (&As)[2][2048], short (&Bs)[2][4096]) {
    const int tid  = threadIdx.x;
    const int lane = tid & 63, wave = tid >> 6;
    const int l16  = lane & 15, lq = lane >> 4;
    const int r_a = tid >> 2, c_a = tid & 3;

    floatx4 sA0[2], sA1[2];

    auto loadA = [&](int kk, int s) {
        const float* g = Av + (row0 + r_a) * 256 + kk * 32 + c_a * 8;
        sA0[s] = *(const floatx4*)g;
        sA1[s] = *(const floatx4*)(g + 4);
    };
    auto writeA = [&](int buf, int s) {
        *(short8*)&As[buf][r_a * 32 + ((c_a ^ (r_a & 3)) << 3)] = cvt_pk8(sA0[s], sA1[s]);
    };
    auto stageB = [&](int kk, int buf) {
#pragma unroll
        for (int c2 = 0; c2 < 2; ++c2) {
            const int idx = c2 * 256 + tid;
            const int col = idx >> 2, ch = idx & 3;
            const short* g = Bt + (long)col * 256 + kk * 32 + ((ch ^ (col & 3)) << 3);
            async16(&Bs[buf][(c2 * 256 + (wave << 6)) * 8], g);
        }
    };

    floatx4 acc[4][2];
#pragma unroll
    for (int i = 0; i < 4; ++i)
#pragma unroll
        for (int j = 0; j < 2; ++j) acc[i][j] = (floatx4){0.f, 0.f, 0.f, 0.f};

    auto compute = [&](int buf) {
        short8 af[4], bv[2];
#pragma unroll
        for (int mf = 0; mf < 4; ++mf) {
            const int r = mf * 16 + l16;
            af[mf] = *(const short8*)&As[buf][r * 32 + ((lq ^ (r & 3)) << 3)];
        }
#pragma unroll
        for (int nf = 0; nf < 2; ++nf) {
            const int r = wave * 32 + nf * 16 + l16;
            bv[nf] = *(const short8*)&Bs[buf][r * 32 + ((lq ^ (r & 3)) << 3)];
        }
        __builtin_amdgcn_s_setprio(1);
#pragma unroll
        for (int mf = 0; mf < 4; ++mf)
#pragma unroll
            for (int nf = 0; nf < 2; ++nf)
                acc[mf][nf] = __builtin_amdgcn_mfma_f32_16x16x32_bf16(
                    bv[nf], af[mf], acc[mf][nf], 0, 0, 0);   // swapped -> row-major D
        __builtin_amdgcn_s_setprio(0);
    };

    stageB(0, 0);
    loadA(0, 0);
    loadA(1, 1);
    writeA(0, 0);
    wait_vm_lgkm0<2>();
    __builtin_amdgcn_s_barrier();
    __builtin_amdgcn_sched_barrier(0);

#pragma unroll
    for (int k = 0; k < 7; ++k) {
        const int cur = k & 1, nxt = cur ^ 1;
        stageB(k + 1, nxt);
        if (k < 6) loadA(k + 2, k & 1);
        compute(cur);
        writeA(nxt, (k + 1) & 1);
        if (k < 6) wait_vm_lgkm0<2>();
        else       wait_vm_lgkm0<0>();
        __builtin_amdgcn_s_barrier();
        __builtin_amdgcn_sched_barrier(0);
    }
    compute(1);

#pragma unroll
    for (int mf = 0; mf < 4; ++mf) {
        const long grow = row0 + mf * 16 + l16;
#pragma unroll
        for (int nf = 0; nf < 2; ++nf) {
            const int gcol = colbase + wave * 32 + nf * 16 + lq * 4;
            const floatx4 bv4 = *(const floatx4*)(bias + gcol);
            const floatx4 v = acc[mf][nf] + bv4;
            if (OUT_F32) {
                *(floatx4*)((float*)Cv + grow * Ntot + gcol) = v;
            } else {
                bfx4 s;
#pragma unroll
                for (int r = 0; r < 4; ++r) s[r] = (short)f2bf(v[r]);
                *(bfx4*)((short*)Cv + grow * Ntot + gcol) = s;
            }
        }
    }
}

// ---------------------------------------------------------------------------
// gemm_mega: value + offattn GEMMs fused (block classes), 24KB LDS blocks.
//   Blocks [0,2720): value (row-tile = bid>>1, colgroup = bid&1)
//   Blocks [2720,2976): off cols 0..255 (row-tile, colgroup)
//   Blocks [2976,3104): attn cols 256..383
// ---------------------------------------------------------------------------
__global__ __launch_bounds__(256, 4) void gemm_mega(
        const float* __restrict__ sfeats, const float* __restrict__ in_feats,
        const short* __restrict__ Wvt, const short* __restrict__ Wcat,
        const float* __restrict__ b_val, const float* __restrict__ bcat,
        short* __restrict__ value, float* __restrict__ offattn) {
    __shared__ short As[2][2048];    // 8 KB
    __shared__ short Bs[2][4096];    // 16 KB

    const int bid = blockIdx.x;
    const int nval = (B_ * S_) / 32;                 // 2720 (1360 tiles x 2 cg)
    if (bid < nval) {
        const int tile = bid >> 1, cg = bid & 1;
        gemm_core<0>(sfeats, Wvt + cg * 32768, b_val, (void*)value,
                     (long)tile * 64, 256, cg * 128, As, Bs);
    } else if (bid < nval + 256) {
        const int r = bid - nval;
        const int tile = r >> 1, cg = r & 1;
        gemm_core<1>(in_feats, Wcat + cg * 32768, bcat, (void*)offattn,
                     (long)tile * 64, 384, cg * 128, As, Bs);
    } else {
        const int tile = bid - nval - 256;
        gemm_core<1>(in_feats, Wcat + 65536, bcat, (void*)offattn,
                     (long)tile * 64, 384, 256, As, Bs);
    }
}

// ---------------------------------------------------------------------------
// sampler_out: softmax + deformable gather + OUT GEMM fused (r14 verified).
// ---------------------------------------------------------------------------
__global__ __launch_bounds__(512) void sampler_out(
        const float* __restrict__ priors,
        const int* __restrict__ shapes, const int* __restrict__ starts,
        const float* __restrict__ offattn,
        const short* __restrict__ value,
        const short* __restrict__ Wof, const float* __restrict__ b_out,
        float* __restrict__ out) {
    __shared__ float oa_lds[16][384];
    __shared__ short wv_lds[16][256];   // 8 KB, chunk c stored at c^(row&7)
    __shared__ float pri_lds[16][4][2];
    __shared__ int   shp_lds[4][2];
    __shared__ int   st_lds[4];

    const int tid = threadIdx.x;
    const int b   = blockIdx.x >> 7;
    const int qt  = blockIdx.x & 127;
    const long q0 = (long)qt * 16;

    const float* src = offattn + ((long)b * Qn_ + q0) * 384;
    for (int i = tid; i < 16 * 384 / 4; i += 512)
        ((floatx4*)oa_lds)[i] = ((const floatx4*)src)[i];
    if (tid < 128) ((float*)pri_lds)[tid] = priors[((long)b * Qn_ + q0) * 8 + tid];
    if (tid < 8)  ((int*)shp_lds)[tid] = shapes[tid];
    if (tid < 4)  st_lds[tid] = starts[tid];
    __syncthreads();

    if (tid < 128) {
        const int qi = tid >> 3, h = tid & 7;
        float* a = &oa_lds[qi][256 + h * 16];
        float m = a[0];
        for (int i = 1; i < 16; ++i) m = fmaxf(m, a[i]);
        float s = 0.f;
        for (int i = 0; i < 16; ++i) { float e = expf(a[i] - m); a[i] = e; s += e; }
        const float inv = 1.f / s;
        for (int i = 0; i < 16; ++i) a[i] *= inv;
    }
    __syncthreads();

    // ---- sampling: thread (qi, h, sub) -> 8 channels; wv -> LDS ----
    {
        const int pairi = tid >> 2, sub = tid & 3;
        const int qi = pairi >> 3, h = pairi & 7;
        float acc[8];
#pragma unroll
        for (int j = 0; j < 8; ++j) acc[j] = 0.f;
        const short* vbase = value + (long)b * S_ * 256 + h * 32 + sub * 8;

        for (int l = 0; l < 4; ++l) {
            const int Hl = shp_lds[l][0], Wl = shp_lds[l][1];
            const int st = st_lds[l];
            const float px = pri_lds[qi][l][0], py = pri_lds[qi][l][1];
            const float invW = 1.f / (float)Wl, invH = 1.f / (float)Hl;

            float wgt[16];
            int   off[16];
#pragma unroll
            for (int p = 0; p < 4; ++p) {
                const int cb = h * 16 + l * 4 + p;
                const float ox = oa_lds[qi][cb * 2], oy = oa_lds[qi][cb * 2 + 1];
                const float lx = px + ox * invW, ly = py + oy * invH;
                const float ix = lx * (float)Wl - 0.5f, iy = ly * (float)Hl - 0.5f;
                const float x0f = floorf(ix), y0f = floorf(iy);
                const int x0 = (int)x0f, y0 = (int)y0f;
                const float fx = ix - x0f, fy = iy - y0f;
                const float awv = oa_lds[qi][256 + cb];
#pragma unroll
                for (int dy = 0; dy < 2; ++dy) {
                    const int yc = y0 + dy;
                    const float wy = dy ? fy : 1.f - fy;
                    const int yi = min(max(yc, 0), Hl - 1);
#pragma unroll
                    for (int dx = 0; dx < 2; ++dx) {
                        const int xc = x0 + dx;
                        const float wx = dx ? fx : 1.f - fx;
                        const int xi = min(max(xc, 0), Wl - 1);
                        const bool v = (xc >= 0) & (xc < Wl) & (yc >= 0) & (yc < Hl);
                        const int j = p * 4 + dy * 2 + dx;
                        wgt[j] = v ? wy * wx * awv : 0.f;
                        off[j] = yi * Wl + xi;
                    }
                }
            }
            const short* base = vbase + (long)st * 256;
            short8 vv[16];
#pragma unroll
            for (int j = 0; j < 16; ++j)
                vv[j] = *(const short8*)(base + (long)off[j] * 256);
#pragma unroll
            for (int j = 0; j < 16; ++j) {
                const float w = wgt[j];
#pragma unroll
                for (int c = 0; c < 8; ++c) acc[c] += w * bf2f((unsigned short)vv[j][c]);
            }
        }

        short8 ov;
#pragma unroll
        for (int j = 0; j < 8; ++j) ov[j] = (short)f2bf(acc[j]);
        const int chunk = (h * 4 + sub) ^ (qi & 7);       // XOR swizzle
        *(short8*)&wv_lds[qi][chunk * 8] = ov;
    }
    __syncthreads();

    // ---- out GEMM: wave w -> cols w*32 .. +31 (16 reg-operand MFMAs) ----
    {
        const int lane = tid & 63, w = tid >> 6;
        const int l16 = lane & 15, lq = lane >> 4;

        short8 bfrag[8][2];
#pragma unroll
        for (int kc = 0; kc < 8; ++kc)
#pragma unroll
            for (int nf = 0; nf < 2; ++nf)
                bfrag[kc][nf] = *(const short8*)(
                    Wof + (long)((kc * 16 + w * 2 + nf) * 64 + lane) * 8);

        short8 af[8];
#pragma unroll
        for (int kc = 0; kc < 8; ++kc) {
            const int chunk = (kc * 4 + lq) ^ (l16 & 7);
            af[kc] = *(const short8*)&wv_lds[l16][chunk * 8];
        }

        floatx4 acc2[2];
#pragma unroll
        for (int nf = 0; nf < 2; ++nf) acc2[nf] = (floatx4){0.f, 0.f, 0.f, 0.f};
#pragma unroll
        for (int kc = 0; kc < 8; ++kc)
#pragma unroll
            for (int nf = 0; nf < 2; ++nf)
                acc2[nf] = __builtin_amdgcn_mfma_f32_16x16x32_bf16(
                    bfrag[kc][nf], af[kc], acc2[nf], 0, 0, 0);  // swapped -> row-major

        float* co = out + ((long)b * Qn_ + q0 + l16) * 256 + w * 32 + lq * 4;
#pragma unroll
        for (int nf = 0; nf < 2; ++nf) {
            const floatx4 bv4 = *(const floatx4*)(b_out + w * 32 + nf * 16 + lq * 4);
            *(floatx4*)(co + nf * 16) = acc2[nf] + bv4;
        }
    }
}

// ---------------------------------------------------------------------------
extern "C" void kernel_launch(void* const* d_in, const int* in_sizes, int n_in,
                              void* d_out, int out_size, void* d_ws, size_t ws_size,
                              hipStream_t stream) {
    const float* in_feats = (const float*)d_in[0];
    const float* priors   = (const float*)d_in[1];
    const float* sfeats   = (const float*)d_in[2];
    const int*   shapes   = (const int*)d_in[3];
    const int*   starts   = (const int*)d_in[4];
    const float* W_off    = (const float*)d_in[5];
    const float* b_off    = (const float*)d_in[6];
    const float* W_attn   = (const float*)d_in[7];
    const float* b_attn   = (const float*)d_in[8];
    const float* W_val    = (const float*)d_in[9];
    const float* b_val    = (const float*)d_in[10];
    const float* W_out    = (const float*)d_in[11];
    const float* b_out    = (const float*)d_in[12];
    float* out = (float*)d_out;

    // Workspace: Wvt 128K | Wof 128K | Wcat 192K | value 44.56M (short)
    //            offattn 12.58M | bcat 1.5K (f32)
    short* Wvt     = (short*)d_ws;
    short* Wof     = Wvt + 65536;
    short* Wcat    = Wof + 65536;
    short* value   = Wcat + 98304;
    float* offattn = (float*)(value + (long)B_ * S_ * 256);
    float* bcat    = offattn + (long)B_ * Qn_ * 384;

    // all weight prep in one dispatch
    prep_all<<<320, 1024, 0, stream>>>(W_val, W_out, W_off, W_attn, b_off, b_attn,
                                       Wvt, Wcat, Wof, bcat);
    // value GEMM + offattn GEMM fused (one dispatch, 24KB-LDS blocks)
    gemm_mega<<<(B_ * S_) / 32 + 256 + 128, 256, 0, stream>>>(
        sfeats, in_feats, Wvt, Wcat, b_val, bcat, value, offattn);
    // softmax + deformable sampling + out GEMM fused
    sampler_out<<<B_ * (Qn_ / 16), 512, 0, stream>>>(
        priors, shapes, starts, offattn, value, Wof, b_out, out);
}

// Round 17
// 82.223 us; speedup vs baseline: 1.0946x; 1.0946x over previous
//
#include <hip/hip_runtime.h>
#include <hip/hip_bf16.h>

// Problem constants (fixed by reference)
#define B_    4
#define Qn_   2048
#define S_    21760   // 128*128 + 64*64 + 32*32 + 16*16

typedef short  bfx4    __attribute__((ext_vector_type(4)));
typedef short  short8  __attribute__((ext_vector_type(8)));
typedef float  floatx4 __attribute__((ext_vector_type(4)));

__device__ __forceinline__ unsigned short f2bf(float f) {
    unsigned int u = __builtin_bit_cast(unsigned int, f);
    u += 0x7fffu + ((u >> 16) & 1u);   // round-to-nearest-even
    return (unsigned short)(u >> 16);
}
__device__ __forceinline__ float bf2f(unsigned short h) {
    unsigned int u = ((unsigned int)h) << 16;
    return __builtin_bit_cast(float, u);
}

// packed f32x8 -> bf16x8 via v_cvt_pk_bf16_f32 (RNE, 1 instr / 2 elems)
__device__ __forceinline__ short8 cvt_pk8(floatx4 f0, floatx4 f1) {
    union { unsigned int u[4]; short8 s; } r;
    asm("v_cvt_pk_bf16_f32 %0, %1, %2" : "=v"(r.u[0]) : "v"(f0[0]), "v"(f0[1]));
    asm("v_cvt_pk_bf16_f32 %0, %1, %2" : "=v"(r.u[1]) : "v"(f0[2]), "v"(f0[3]));
    asm("v_cvt_pk_bf16_f32 %0, %1, %2" : "=v"(r.u[2]) : "v"(f1[0]), "v"(f1[1]));
    asm("v_cvt_pk_bf16_f32 %0, %1, %2" : "=v"(r.u[3]) : "v"(f1[2]), "v"(f1[3]));
    return r.s;
}

// async global->LDS, 16B per lane. lds must be WAVE-UNIFORM base (lane*16 implicit).
__device__ __forceinline__ void async16(void* lds, const void* g) {
    __builtin_amdgcn_global_load_lds(
        (const __attribute__((address_space(1))) unsigned int*)g,
        (__attribute__((address_space(3))) unsigned int*)lds, 16, 0, 0);
}

template<int N>
__device__ __forceinline__ void wait_vm_lgkm0() {
    asm volatile("s_waitcnt vmcnt(%0) lgkmcnt(0)" :: "n"(N) : "memory");
}

// ---------------------------------------------------------------------------
// prep_all: ONE dispatch for all weight prep (r15 verified).
// ---------------------------------------------------------------------------
__global__ __launch_bounds__(1024) void prep_all(
        const float* __restrict__ Wv, const float* __restrict__ Wo,
        const float* __restrict__ Woff, const float* __restrict__ Wattn,
        const float* __restrict__ boff, const float* __restrict__ battn,
        short* __restrict__ Wvt, short* __restrict__ Wcat,
        short* __restrict__ Wof, float* __restrict__ bcat) {
    const int bid = blockIdx.x;
    const int t   = threadIdx.x;
    if (bid < 256) {
        const int k = bid;
        if (t < 256) {
            Wvt[t * 256 + k] = (short)f2bf(Wv[k * 256 + t]);
        } else if (t < 640) {
            const int n = t - 256;     // 0..383
            const float w = (n < 256) ? Woff[k * 256 + n] : Wattn[k * 128 + (n - 256)];
            Wcat[n * 256 + k] = (short)f2bf(w);
        }
        if (bid == 0 && t < 384)
            bcat[t] = (t < 256) ? boff[t] : battn[t - 256];
    } else {
        const int g = (bid - 256) * 1024 + t;   // 0..65535
        const int j  = g & 7;
        const int l  = (g >> 3) & 63;
        const int nf = (g >> 9) & 15;
        const int kc = g >> 13;
        const int k = kc * 32 + (l >> 4) * 8 + j;
        const int n = nf * 16 + (l & 15);
        Wof[g] = (short)f2bf(Wo[k * 256 + n]);
    }
}

// ---------------------------------------------------------------------------
// gemm_core: the verified v8 inner structure, parameterized (r15 config).
//   BM=64 rows, BN = NF*64 cols, 4 waves.  A f32 reg+cvt_pk staged; B bf16
//   NxK via global_load_lds; 2-phase K-loop, counted vmcnt(2).
//   r17: + s_setprio(1) around MFMA cluster (T5; single isolated variable).
// ---------------------------------------------------------------------------
template<int NF, int OUT_F32>
__device__ __forceinline__ void gemm_core(
        const float* __restrict__ Av, const short* __restrict__ Bt,
        const float* __restrict__ bias, void* __restrict__ Cv,
        long row0, int Ntot, int colbase,
        short (&As)[2][2048], short (&Bs)[2][8192]) {
    const int tid  = threadIdx.x;
    const int lane = tid & 63, wave = tid >> 6;
    const int l16  = lane & 15, lq = lane >> 4;
    const int r_a = tid >> 2, c_a = tid & 3;

    floatx4 sA0[2], sA1[2];

    auto loadA = [&](int kk, int s) {
        const float* g = Av + (row0 + r_a) * 256 + kk * 32 + c_a * 8;
        sA0[s] = *(const floatx4*)g;
        sA1[s] = *(const floatx4*)(g + 4);
    };
    auto writeA = [&](int buf, int s) {
        *(short8*)&As[buf][r_a * 32 + ((c_a ^ (r_a & 3)) << 3)] = cvt_pk8(sA0[s], sA1[s]);
    };
    auto stageB = [&](int kk, int buf) {
#pragma unroll
        for (int c2 = 0; c2 < NF; ++c2) {
            const int idx = c2 * 256 + tid;
            const int col = idx >> 2, ch = idx & 3;
            const short* g = Bt + (long)col * 256 + kk * 32 + ((ch ^ (col & 3)) << 3);
            async16(&Bs[buf][(c2 * 256 + (wave << 6)) * 8], g);
        }
    };

    floatx4 acc[4][NF];
#pragma unroll
    for (int i = 0; i < 4; ++i)
#pragma unroll
        for (int j = 0; j < NF; ++j) acc[i][j] = (floatx4){0.f, 0.f, 0.f, 0.f};

    auto compute = [&](int buf) {
        short8 af[4], bv[NF];
#pragma unroll
        for (int mf = 0; mf < 4; ++mf) {
            const int r = mf * 16 + l16;
            af[mf] = *(const short8*)&As[buf][r * 32 + ((lq ^ (r & 3)) << 3)];
        }
#pragma unroll
        for (int nf = 0; nf < NF; ++nf) {
            const int r = wave * (NF * 16) + nf * 16 + l16;
            bv[nf] = *(const short8*)&Bs[buf][r * 32 + ((lq ^ (r & 3)) << 3)];
        }
        __builtin_amdgcn_s_setprio(1);
#pragma unroll
        for (int mf = 0; mf < 4; ++mf)
#pragma unroll
            for (int nf = 0; nf < NF; ++nf)
                acc[mf][nf] = __builtin_amdgcn_mfma_f32_16x16x32_bf16(
                    bv[nf], af[mf], acc[mf][nf], 0, 0, 0);   // swapped -> row-major D
        __builtin_amdgcn_s_setprio(0);
    };

    stageB(0, 0);
    loadA(0, 0);
    loadA(1, 1);
    writeA(0, 0);
    wait_vm_lgkm0<2>();
    __builtin_amdgcn_s_barrier();
    __builtin_amdgcn_sched_barrier(0);

#pragma unroll
    for (int k = 0; k < 7; ++k) {
        const int cur = k & 1, nxt = cur ^ 1;
        stageB(k + 1, nxt);
        if (k < 6) loadA(k + 2, k & 1);
        compute(cur);
        writeA(nxt, (k + 1) & 1);
        if (k < 6) wait_vm_lgkm0<2>();
        else       wait_vm_lgkm0<0>();
        __builtin_amdgcn_s_barrier();
        __builtin_amdgcn_sched_barrier(0);
    }
    compute(1);

#pragma unroll
    for (int mf = 0; mf < 4; ++mf) {
        const long grow = row0 + mf * 16 + l16;
#pragma unroll
        for (int nf = 0; nf < NF; ++nf) {
            const int gcol = colbase + wave * (NF * 16) + nf * 16 + lq * 4;
            const floatx4 bv4 = *(const floatx4*)(bias + gcol);
            const floatx4 v = acc[mf][nf] + bv4;
            if (OUT_F32) {
                *(floatx4*)((float*)Cv + grow * Ntot + gcol) = v;
            } else {
                bfx4 s;
#pragma unroll
                for (int r = 0; r < 4; ++r) s[r] = (short)f2bf(v[r]);
                *(bfx4*)((short*)Cv + grow * Ntot + gcol) = s;
            }
        }
    }
}

// ---------------------------------------------------------------------------
// gemm_mega: value + offattn GEMMs fused (block classes), value FIRST.
//   Blocks [0,1360): value tiles                 (core<4,0>, A=sfeats)
//   Blocks [1360,1488): off cols 0..255          (core<4,1>, A=in_feats)
//   Blocks [1488,1616): attn cols 256..383       (core<2,1>, A=in_feats)
//   r15 config: NF=4, 40KB LDS, __launch_bounds__(256,4).
// ---------------------------------------------------------------------------
__global__ __launch_bounds__(256, 4) void gemm_mega(
        const float* __restrict__ sfeats, const float* __restrict__ in_feats,
        const short* __restrict__ Wvt, const short* __restrict__ Wcat,
        const float* __restrict__ b_val, const float* __restrict__ bcat,
        short* __restrict__ value, float* __restrict__ offattn) {
    __shared__ short As[2][2048];    // 8 KB
    __shared__ short Bs[2][8192];    // 32 KB

    const int bid = blockIdx.x;
    const int nval = (B_ * S_) / 64;                 // 1360
    if (bid < nval) {
        gemm_core<4, 0>(sfeats, Wvt, b_val, (void*)value,
                        (long)bid * 64, 256, 0, As, Bs);
    } else if (bid < nval + 128) {
        gemm_core<4, 1>(in_feats, Wcat, bcat, (void*)offattn,
                        (long)(bid - nval) * 64, 384, 0, As, Bs);
    } else {
        gemm_core<2, 1>(in_feats, Wcat + 65536, bcat, (void*)offattn,
                        (long)(bid - nval - 128) * 64, 384, 256, As, Bs);
    }
}

// ---------------------------------------------------------------------------
// sampler_out: softmax + deformable gather + OUT GEMM fused (r14 verified).
// ---------------------------------------------------------------------------
__global__ __launch_bounds__(512) void sampler_out(
        const float* __restrict__ priors,
        const int* __restrict__ shapes, const int* __restrict__ starts,
        const float* __restrict__ offattn,
        const short* __restrict__ value,
        const short* __restrict__ Wof, const float* __restrict__ b_out,
        float* __restrict__ out) {
    __shared__ float oa_lds[16][384];
    __shared__ short wv_lds[16][256];   // 8 KB, chunk c stored at c^(row&7)
    __shared__ float pri_lds[16][4][2];
    __shared__ int   shp_lds[4][2];
    __shared__ int   st_lds[4];

    const int tid = threadIdx.x;
    const int b   = blockIdx.x >> 7;
    const int qt  = blockIdx.x & 127;
    const long q0 = (long)qt * 16;

    const float* src = offattn + ((long)b * Qn_ + q0) * 384;
    for (int i = tid; i < 16 * 384 / 4; i += 512)
        ((floatx4*)oa_lds)[i] = ((const floatx4*)src)[i];
    if (tid < 128) ((float*)pri_lds)[tid] = priors[((long)b * Qn_ + q0) * 8 + tid];
    if (tid < 8)  ((int*)shp_lds)[tid] = shapes[tid];
    if (tid < 4)  st_lds[tid] = starts[tid];
    __syncthreads();

    if (tid < 128) {
        const int qi = tid >> 3, h = tid & 7;
        float* a = &oa_lds[qi][256 + h * 16];
        float m = a[0];
        for (int i = 1; i < 16; ++i) m = fmaxf(m, a[i]);
        float s = 0.f;
        for (int i = 0; i < 16; ++i) { float e = expf(a[i] - m); a[i] = e; s += e; }
        const float inv = 1.f / s;
        for (int i = 0; i < 16; ++i) a[i] *= inv;
    }
    __syncthreads();

    // ---- sampling: thread (qi, h, sub) -> 8 channels; wv -> LDS ----
    {
        const int pairi = tid >> 2, sub = tid & 3;
        const int qi = pairi >> 3, h = pairi & 7;
        float acc[8];
#pragma unroll
        for (int j = 0; j < 8; ++j) acc[j] = 0.f;
        const short* vbase = value + (long)b * S_ * 256 + h * 32 + sub * 8;

        for (int l = 0; l < 4; ++l) {
            const int Hl = shp_lds[l][0], Wl = shp_lds[l][1];
            const int st = st_lds[l];
            const float px = pri_lds[qi][l][0], py = pri_lds[qi][l][1];
            const float invW = 1.f / (float)Wl, invH = 1.f / (float)Hl;

            float wgt[16];
            int   off[16];
#pragma unroll
            for (int p = 0; p < 4; ++p) {
                const int cb = h * 16 + l * 4 + p;
                const float ox = oa_lds[qi][cb * 2], oy = oa_lds[qi][cb * 2 + 1];
                const float lx = px + ox * invW, ly = py + oy * invH;
                const float ix = lx * (float)Wl - 0.5f, iy = ly * (float)Hl - 0.5f;
                const float x0f = floorf(ix), y0f = floorf(iy);
                const int x0 = (int)x0f, y0 = (int)y0f;
                const float fx = ix - x0f, fy = iy - y0f;
                const float awv = oa_lds[qi][256 + cb];
#pragma unroll
                for (int dy = 0; dy < 2; ++dy) {
                    const int yc = y0 + dy;
                    const float wy = dy ? fy : 1.f - fy;
                    const int yi = min(max(yc, 0), Hl - 1);
#pragma unroll
                    for (int dx = 0; dx < 2; ++dx) {
                        const int xc = x0 + dx;
                        const float wx = dx ? fx : 1.f - fx;
                        const int xi = min(max(xc, 0), Wl - 1);
                        const bool v = (xc >= 0) & (xc < Wl) & (yc >= 0) & (yc < Hl);
                        const int j = p * 4 + dy * 2 + dx;
                        wgt[j] = v ? wy * wx * awv : 0.f;
                        off[j] = yi * Wl + xi;
                    }
                }
            }
            const short* base = vbase + (long)st * 256;
            short8 vv[16];
#pragma unroll
            for (int j = 0; j < 16; ++j)
                vv[j] = *(const short8*)(base + (long)off[j] * 256);
#pragma unroll
            for (int j = 0; j < 16; ++j) {
                const float w = wgt[j];
#pragma unroll
                for (int c = 0; c < 8; ++c) acc[c] += w * bf2f((unsigned short)vv[j][c]);
            }
        }

        short8 ov;
#pragma unroll
        for (int j = 0; j < 8; ++j) ov[j] = (short)f2bf(acc[j]);
        const int chunk = (h * 4 + sub) ^ (qi & 7);       // XOR swizzle
        *(short8*)&wv_lds[qi][chunk * 8] = ov;
    }
    __syncthreads();

    // ---- out GEMM: wave w -> cols w*32 .. +31 (16 reg-operand MFMAs) ----
    {
        const int lane = tid & 63, w = tid >> 6;
        const int l16 = lane & 15, lq = lane >> 4;

        short8 bfrag[8][2];
#pragma unroll
        for (int kc = 0; kc < 8; ++kc)
#pragma unroll
            for (int nf = 0; nf < 2; ++nf)
                bfrag[kc][nf] = *(const short8*)(
                    Wof + (long)((kc * 16 + w * 2 + nf) * 64 + lane) * 8);

        short8 af[8];
#pragma unroll
        for (int kc = 0; kc < 8; ++kc) {
            const int chunk = (kc * 4 + lq) ^ (l16 & 7);
            af[kc] = *(const short8*)&wv_lds[l16][chunk * 8];
        }

        floatx4 acc2[2];
#pragma unroll
        for (int nf = 0; nf < 2; ++nf) acc2[nf] = (floatx4){0.f, 0.f, 0.f, 0.f};
#pragma unroll
        for (int kc = 0; kc < 8; ++kc)
#pragma unroll
            for (int nf = 0; nf < 2; ++nf)
                acc2[nf] = __builtin_amdgcn_mfma_f32_16x16x32_bf16(
                    bfrag[kc][nf], af[kc], acc2[nf], 0, 0, 0);  // swapped -> row-major

        float* co = out + ((long)b * Qn_ + q0 + l16) * 256 + w * 32 + lq * 4;
#pragma unroll
        for (int nf = 0; nf < 2; ++nf) {
            const floatx4 bv4 = *(const floatx4*)(b_out + w * 32 + nf * 16 + lq * 4);
            *(floatx4*)(co + nf * 16) = acc2[nf] + bv4;
        }
    }
}

// ---------------------------------------------------------------------------
extern "C" void kernel_launch(void* const* d_in, const int* in_sizes, int n_in,
                              void* d_out, int out_size, void* d_ws, size_t ws_size,
                              hipStream_t stream) {
    const float* in_feats = (const float*)d_in[0];
    const float* priors   = (const float*)d_in[1];
    const float* sfeats   = (const float*)d_in[2];
    const int*   shapes   = (const int*)d_in[3];
    const int*   starts   = (const int*)d_in[4];
    const float* W_off    = (const float*)d_in[5];
    const float* b_off    = (const float*)d_in[6];
    const float* W_attn   = (const float*)d_in[7];
    const float* b_attn   = (const float*)d_in[8];
    const float* W_val    = (const float*)d_in[9];
    const float* b_val    = (const float*)d_in[10];
    const float* W_out    = (const float*)d_in[11];
    const float* b_out    = (const float*)d_in[12];
    float* out = (float*)d_out;

    // Workspace: Wvt 128K | Wof 128K | Wcat 192K | value 44.56M (short)
    //            offattn 12.58M | bcat 1.5K (f32)
    short* Wvt     = (short*)d_ws;
    short* Wof     = Wvt + 65536;
    short* Wcat    = Wof + 65536;
    short* value   = Wcat + 98304;
    float* offattn = (float*)(value + (long)B_ * S_ * 256);
    float* bcat    = offattn + (long)B_ * Qn_ * 384;

    // all weight prep in one dispatch
    prep_all<<<320, 1024, 0, stream>>>(W_val, W_out, W_off, W_attn, b_off, b_attn,
                                       Wvt, Wcat, Wof, bcat);
    // value GEMM + offattn GEMM fused (one dispatch, value blocks first)
    gemm_mega<<<256 + (B_ * S_) / 64, 256, 0, stream>>>(
        sfeats, in_feats, Wvt, Wcat, b_val, bcat, value, offattn);
    // softmax + deformable sampling + out GEMM fused
    sampler_out<<<B_ * (Qn_ / 16), 512, 0, stream>>>(
        priors, shapes, starts, offattn, value, Wof, b_out, out);
}

// Round 18
// 80.660 us; speedup vs baseline: 1.1158x; 1.0194x over previous
//
#include <hip/hip_runtime.h>
#include <hip/hip_bf16.h>

// Problem constants (fixed by reference)
#define B_    4
#define Qn_   2048
#define S_    21760   // 128*128 + 64*64 + 32*32 + 16*16

typedef short  bfx4    __attribute__((ext_vector_type(4)));
typedef short  short8  __attribute__((ext_vector_type(8)));
typedef float  floatx4 __attribute__((ext_vector_type(4)));

__device__ __forceinline__ unsigned short f2bf(float f) {
    unsigned int u = __builtin_bit_cast(unsigned int, f);
    u += 0x7fffu + ((u >> 16) & 1u);   // round-to-nearest-even
    return (unsigned short)(u >> 16);
}
__device__ __forceinline__ float bf2f(unsigned short h) {
    unsigned int u = ((unsigned int)h) << 16;
    return __builtin_bit_cast(float, u);
}

// packed f32x8 -> bf16x8 via v_cvt_pk_bf16_f32 (RNE, 1 instr / 2 elems)
__device__ __forceinline__ short8 cvt_pk8(floatx4 f0, floatx4 f1) {
    union { unsigned int u[4]; short8 s; } r;
    asm("v_cvt_pk_bf16_f32 %0, %1, %2" : "=v"(r.u[0]) : "v"(f0[0]), "v"(f0[1]));
    asm("v_cvt_pk_bf16_f32 %0, %1, %2" : "=v"(r.u[1]) : "v"(f0[2]), "v"(f0[3]));
    asm("v_cvt_pk_bf16_f32 %0, %1, %2" : "=v"(r.u[2]) : "v"(f1[0]), "v"(f1[1]));
    asm("v_cvt_pk_bf16_f32 %0, %1, %2" : "=v"(r.u[3]) : "v"(f1[2]), "v"(f1[3]));
    return r.s;
}

// async global->LDS, 16B per lane. lds must be WAVE-UNIFORM base (lane*16 implicit).
__device__ __forceinline__ void async16(void* lds, const void* g) {
    __builtin_amdgcn_global_load_lds(
        (const __attribute__((address_space(1))) unsigned int*)g,
        (__attribute__((address_space(3))) unsigned int*)lds, 16, 0, 0);
}

template<int N>
__device__ __forceinline__ void wait_vm_lgkm0() {
    asm volatile("s_waitcnt vmcnt(%0) lgkmcnt(0)" :: "n"(N) : "memory");
}

// ---------------------------------------------------------------------------
// prep_all: ONE dispatch for all weight prep (r15 verified).
// ---------------------------------------------------------------------------
__global__ __launch_bounds__(1024) void prep_all(
        const float* __restrict__ Wv, const float* __restrict__ Wo,
        const float* __restrict__ Woff, const float* __restrict__ Wattn,
        const float* __restrict__ boff, const float* __restrict__ battn,
        short* __restrict__ Wvt, short* __restrict__ Wcat,
        short* __restrict__ Wof, float* __restrict__ bcat) {
    const int bid = blockIdx.x;
    const int t   = threadIdx.x;
    if (bid < 256) {
        const int k = bid;
        if (t < 256) {
            Wvt[t * 256 + k] = (short)f2bf(Wv[k * 256 + t]);
        } else if (t < 640) {
            const int n = t - 256;     // 0..383
            const float w = (n < 256) ? Woff[k * 256 + n] : Wattn[k * 128 + (n - 256)];
            Wcat[n * 256 + k] = (short)f2bf(w);
        }
        if (bid == 0 && t < 384)
            bcat[t] = (t < 256) ? boff[t] : battn[t - 256];
    } else {
        const int g = (bid - 256) * 1024 + t;   // 0..65535
        const int j  = g & 7;
        const int l  = (g >> 3) & 63;
        const int nf = (g >> 9) & 15;
        const int kc = g >> 13;
        const int k = kc * 32 + (l >> 4) * 8 + j;
        const int n = nf * 16 + (l & 15);
        Wof[g] = (short)f2bf(Wo[k * 256 + n]);
    }
}

// ---------------------------------------------------------------------------
// gemm_core: the verified v8 inner structure, parameterized (r15 config,
//   setprio removed -- r17 A/B showed it regresses this lockstep loop).
//   BM=64 rows, BN = NF*64 cols, 4 waves.  A f32 reg+cvt_pk staged; B bf16
//   NxK via global_load_lds; 2-phase K-loop, counted vmcnt(2).
// ---------------------------------------------------------------------------
template<int NF, int OUT_F32>
__device__ __forceinline__ void gemm_core(
        const float* __restrict__ Av, const short* __restrict__ Bt,
        const float* __restrict__ bias, void* __restrict__ Cv,
        long row0, int Ntot, int colbase,
        short (&As)[2][2048], short (&Bs)[2][8192]) {
    const int tid  = threadIdx.x;
    const int lane = tid & 63, wave = tid >> 6;
    const int l16  = lane & 15, lq = lane >> 4;
    const int r_a = tid >> 2, c_a = tid & 3;

    floatx4 sA0[2], sA1[2];

    auto loadA = [&](int kk, int s) {
        const float* g = Av + (row0 + r_a) * 256 + kk * 32 + c_a * 8;
        sA0[s] = *(const floatx4*)g;
        sA1[s] = *(const floatx4*)(g + 4);
    };
    auto writeA = [&](int buf, int s) {
        *(short8*)&As[buf][r_a * 32 + ((c_a ^ (r_a & 3)) << 3)] = cvt_pk8(sA0[s], sA1[s]);
    };
    auto stageB = [&](int kk, int buf) {
#pragma unroll
        for (int c2 = 0; c2 < NF; ++c2) {
            const int idx = c2 * 256 + tid;
            const int col = idx >> 2, ch = idx & 3;
            const short* g = Bt + (long)col * 256 + kk * 32 + ((ch ^ (col & 3)) << 3);
            async16(&Bs[buf][(c2 * 256 + (wave << 6)) * 8], g);
        }
    };

    floatx4 acc[4][NF];
#pragma unroll
    for (int i = 0; i < 4; ++i)
#pragma unroll
        for (int j = 0; j < NF; ++j) acc[i][j] = (floatx4){0.f, 0.f, 0.f, 0.f};

    auto compute = [&](int buf) {
        short8 af[4], bv[NF];
#pragma unroll
        for (int mf = 0; mf < 4; ++mf) {
            const int r = mf * 16 + l16;
            af[mf] = *(const short8*)&As[buf][r * 32 + ((lq ^ (r & 3)) << 3)];
        }
#pragma unroll
        for (int nf = 0; nf < NF; ++nf) {
            const int r = wave * (NF * 16) + nf * 16 + l16;
            bv[nf] = *(const short8*)&Bs[buf][r * 32 + ((lq ^ (r & 3)) << 3)];
        }
#pragma unroll
        for (int mf = 0; mf < 4; ++mf)
#pragma unroll
            for (int nf = 0; nf < NF; ++nf)
                acc[mf][nf] = __builtin_amdgcn_mfma_f32_16x16x32_bf16(
                    bv[nf], af[mf], acc[mf][nf], 0, 0, 0);   // swapped -> row-major D
    };

    stageB(0, 0);
    loadA(0, 0);
    loadA(1, 1);
    writeA(0, 0);
    wait_vm_lgkm0<2>();
    __builtin_amdgcn_s_barrier();
    __builtin_amdgcn_sched_barrier(0);

#pragma unroll
    for (int k = 0; k < 7; ++k) {
        const int cur = k & 1, nxt = cur ^ 1;
        stageB(k + 1, nxt);
        if (k < 6) loadA(k + 2, k & 1);
        compute(cur);
        writeA(nxt, (k + 1) & 1);
        if (k < 6) wait_vm_lgkm0<2>();
        else       wait_vm_lgkm0<0>();
        __builtin_amdgcn_s_barrier();
        __builtin_amdgcn_sched_barrier(0);
    }
    compute(1);

#pragma unroll
    for (int mf = 0; mf < 4; ++mf) {
        const long grow = row0 + mf * 16 + l16;
#pragma unroll
        for (int nf = 0; nf < NF; ++nf) {
            const int gcol = colbase + wave * (NF * 16) + nf * 16 + lq * 4;
            const floatx4 bv4 = *(const floatx4*)(bias + gcol);
            const floatx4 v = acc[mf][nf] + bv4;
            if (OUT_F32) {
                *(floatx4*)((float*)Cv + grow * Ntot + gcol) = v;
            } else {
                bfx4 s;
#pragma unroll
                for (int r = 0; r < 4; ++r) s[r] = (short)f2bf(v[r]);
                *(bfx4*)((short*)Cv + grow * Ntot + gcol) = s;
            }
        }
    }
}

// ---------------------------------------------------------------------------
// gemm_mega: value + offattn GEMMs fused (block classes), value FIRST.
//   Blocks [0,1360): value tiles                 (core<4,0>, A=sfeats)
//   Blocks [1360,1488): off cols 0..255          (core<4,1>, A=in_feats)
//   Blocks [1488,1616): attn cols 256..383       (core<2,1>, A=in_feats)
//   r15 config: NF=4, 40KB LDS, __launch_bounds__(256,4).
// ---------------------------------------------------------------------------
__global__ __launch_bounds__(256, 4) void gemm_mega(
        const float* __restrict__ sfeats, const float* __restrict__ in_feats,
        const short* __restrict__ Wvt, const short* __restrict__ Wcat,
        const float* __restrict__ b_val, const float* __restrict__ bcat,
        short* __restrict__ value, float* __restrict__ offattn) {
    __shared__ short As[2][2048];    // 8 KB
    __shared__ short Bs[2][8192];    // 32 KB

    const int bid = blockIdx.x;
    const int nval = (B_ * S_) / 64;                 // 1360
    if (bid < nval) {
        gemm_core<4, 0>(sfeats, Wvt, b_val, (void*)value,
                        (long)bid * 64, 256, 0, As, Bs);
    } else if (bid < nval + 128) {
        gemm_core<4, 1>(in_feats, Wcat, bcat, (void*)offattn,
                        (long)(bid - nval) * 64, 384, 0, As, Bs);
    } else {
        gemm_core<2, 1>(in_feats, Wcat + 65536, bcat, (void*)offattn,
                        (long)(bid - nval - 128) * 64, 384, 256, As, Bs);
    }
}

// ---------------------------------------------------------------------------
// sampler_out: softmax + deformable gather + OUT GEMM fused.
//   r18: softmax wave-parallelized -- all 512 threads, 4 lanes per (qi,h)
//   row (each owns a floatx4 quarter), row max/sum via __shfl_xor(1,2)
//   within the 4-lane group (Common-mistake #6 fix).
// ---------------------------------------------------------------------------
__global__ __launch_bounds__(512) void sampler_out(
        const float* __restrict__ priors,
        const int* __restrict__ shapes, const int* __restrict__ starts,
        const float* __restrict__ offattn,
        const short* __restrict__ value,
        const short* __restrict__ Wof, const float* __restrict__ b_out,
        float* __restrict__ out) {
    __shared__ float oa_lds[16][384];
    __shared__ short wv_lds[16][256];   // 8 KB, chunk c stored at c^(row&7)
    __shared__ float pri_lds[16][4][2];
    __shared__ int   shp_lds[4][2];
    __shared__ int   st_lds[4];

    const int tid = threadIdx.x;
    const int b   = blockIdx.x >> 7;
    const int qt  = blockIdx.x & 127;
    const long q0 = (long)qt * 16;

    const float* src = offattn + ((long)b * Qn_ + q0) * 384;
    for (int i = tid; i < 16 * 384 / 4; i += 512)
        ((floatx4*)oa_lds)[i] = ((const floatx4*)src)[i];
    if (tid < 128) ((float*)pri_lds)[tid] = priors[((long)b * Qn_ + q0) * 8 + tid];
    if (tid < 8)  ((int*)shp_lds)[tid] = shapes[tid];
    if (tid < 4)  st_lds[tid] = starts[tid];
    __syncthreads();

    // ---- wave-parallel softmax: 4 lanes per (qi,h) row of 16 logits ----
    {
        const int pair = tid >> 2;            // 0..127 -> (qi, h)
        const int qi = pair >> 3, h = pair & 7;
        const int quarter = tid & 3;
        float* ap = &oa_lds[qi][256 + h * 16 + quarter * 4];
        floatx4 a = *(floatx4*)ap;
        float m = fmaxf(fmaxf(a[0], a[1]), fmaxf(a[2], a[3]));
        m = fmaxf(m, __shfl_xor(m, 1));
        m = fmaxf(m, __shfl_xor(m, 2));
        floatx4 e;
#pragma unroll
        for (int i = 0; i < 4; ++i) e[i] = expf(a[i] - m);
        float s = e[0] + e[1] + e[2] + e[3];
        s += __shfl_xor(s, 1);
        s += __shfl_xor(s, 2);
        const float inv = 1.f / s;
#pragma unroll
        for (int i = 0; i < 4; ++i) e[i] *= inv;
        *(floatx4*)ap = e;
    }
    __syncthreads();

    // ---- sampling: thread (qi, h, sub) -> 8 channels; wv -> LDS ----
    {
        const int pairi = tid >> 2, sub = tid & 3;
        const int qi = pairi >> 3, h = pairi & 7;
        float acc[8];
#pragma unroll
        for (int j = 0; j < 8; ++j) acc[j] = 0.f;
        const short* vbase = value + (long)b * S_ * 256 + h * 32 + sub * 8;

        for (int l = 0; l < 4; ++l) {
            const int Hl = shp_lds[l][0], Wl = shp_lds[l][1];
            const int st = st_lds[l];
            const float px = pri_lds[qi][l][0], py = pri_lds[qi][l][1];
            const float invW = 1.f / (float)Wl, invH = 1.f / (float)Hl;

            float wgt[16];
            int   off[16];
#pragma unroll
            for (int p = 0; p < 4; ++p) {
                const int cb = h * 16 + l * 4 + p;
                const float ox = oa_lds[qi][cb * 2], oy = oa_lds[qi][cb * 2 + 1];
                const float lx = px + ox * invW, ly = py + oy * invH;
                const float ix = lx * (float)Wl - 0.5f, iy = ly * (float)Hl - 0.5f;
                const float x0f = floorf(ix), y0f = floorf(iy);
                const int x0 = (int)x0f, y0 = (int)y0f;
                const float fx = ix - x0f, fy = iy - y0f;
                const float awv = oa_lds[qi][256 + cb];
#pragma unroll
                for (int dy = 0; dy < 2; ++dy) {
                    const int yc = y0 + dy;
                    const float wy = dy ? fy : 1.f - fy;
                    const int yi = min(max(yc, 0), Hl - 1);
#pragma unroll
                    for (int dx = 0; dx < 2; ++dx) {
                        const int xc = x0 + dx;
                        const float wx = dx ? fx : 1.f - fx;
                        const int xi = min(max(xc, 0), Wl - 1);
                        const bool v = (xc >= 0) & (xc < Wl) & (yc >= 0) & (yc < Hl);
                        const int j = p * 4 + dy * 2 + dx;
                        wgt[j] = v ? wy * wx * awv : 0.f;
                        off[j] = yi * Wl + xi;
                    }
                }
            }
            const short* base = vbase + (long)st * 256;
            short8 vv[16];
#pragma unroll
            for (int j = 0; j < 16; ++j)
                vv[j] = *(const short8*)(base + (long)off[j] * 256);
#pragma unroll
            for (int j = 0; j < 16; ++j) {
                const float w = wgt[j];
#pragma unroll
                for (int c = 0; c < 8; ++c) acc[c] += w * bf2f((unsigned short)vv[j][c]);
            }
        }

        short8 ov;
#pragma unroll
        for (int j = 0; j < 8; ++j) ov[j] = (short)f2bf(acc[j]);
        const int chunk = (h * 4 + sub) ^ (qi & 7);       // XOR swizzle
        *(short8*)&wv_lds[qi][chunk * 8] = ov;
    }
    __syncthreads();

    // ---- out GEMM: wave w -> cols w*32 .. +31 (16 reg-operand MFMAs) ----
    {
        const int lane = tid & 63, w = tid >> 6;
        const int l16 = lane & 15, lq = lane >> 4;

        short8 bfrag[8][2];
#pragma unroll
        for (int kc = 0; kc < 8; ++kc)
#pragma unroll
            for (int nf = 0; nf < 2; ++nf)
                bfrag[kc][nf] = *(const short8*)(
                    Wof + (long)((kc * 16 + w * 2 + nf) * 64 + lane) * 8);

        short8 af[8];
#pragma unroll
        for (int kc = 0; kc < 8; ++kc) {
            const int chunk = (kc * 4 + lq) ^ (l16 & 7);
            af[kc] = *(const short8*)&wv_lds[l16][chunk * 8];
        }

        floatx4 acc2[2];
#pragma unroll
        for (int nf = 0; nf < 2; ++nf) acc2[nf] = (floatx4){0.f, 0.f, 0.f, 0.f};
#pragma unroll
        for (int kc = 0; kc < 8; ++kc)
#pragma unroll
            for (int nf = 0; nf < 2; ++nf)
                acc2[nf] = __builtin_amdgcn_mfma_f32_16x16x32_bf16(
                    bfrag[kc][nf], af[kc], acc2[nf], 0, 0, 0);  // swapped -> row-major

        float* co = out + ((long)b * Qn_ + q0 + l16) * 256 + w * 32 + lq * 4;
#pragma unroll
        for (int nf = 0; nf < 2; ++nf) {
            const floatx4 bv4 = *(const floatx4*)(b_out + w * 32 + nf * 16 + lq * 4);
            *(floatx4*)(co + nf * 16) = acc2[nf] + bv4;
        }
    }
}

// ---------------------------------------------------------------------------
extern "C" void kernel_launch(void* const* d_in, const int* in_sizes, int n_in,
                              void* d_out, int out_size, void* d_ws, size_t ws_size,
                              hipStream_t stream) {
    const float* in_feats = (const float*)d_in[0];
    const float* priors   = (const float*)d_in[1];
    const float* sfeats   = (const float*)d_in[2];
    const int*   shapes   = (const int*)d_in[3];
    const int*   starts   = (const int*)d_in[4];
    const float* W_off    = (const float*)d_in[5];
    const float* b_off    = (const float*)d_in[6];
    const float* W_attn   = (const float*)d_in[7];
    const float* b_attn   = (const float*)d_in[8];
    const float* W_val    = (const float*)d_in[9];
    const float* b_val    = (const float*)d_in[10];
    const float* W_out    = (const float*)d_in[11];
    const float* b_out    = (const float*)d_in[12];
    float* out = (float*)d_out;

    // Workspace: Wvt 128K | Wof 128K | Wcat 192K | value 44.56M (short)
    //            offattn 12.58M | bcat 1.5K (f32)
    short* Wvt     = (short*)d_ws;
    short* Wof     = Wvt + 65536;
    short* Wcat    = Wof + 65536;
    short* value   = Wcat + 98304;
    float* offattn = (float*)(value + (long)B_ * S_ * 256);
    float* bcat    = offattn + (long)B_ * Qn_ * 384;

    // all weight prep in one dispatch
    prep_all<<<320, 1024, 0, stream>>>(W_val, W_out, W_off, W_attn, b_off, b_attn,
                                       Wvt, Wcat, Wof, bcat);
    // value GEMM + offattn GEMM fused (one dispatch, value blocks first)
    gemm_mega<<<256 + (B_ * S_) / 64, 256, 0, stream>>>(
        sfeats, in_feats, Wvt, Wcat, b_val, bcat, value, offattn);
    // softmax + deformable sampling + out GEMM fused
    sampler_out<<<B_ * (Qn_ / 16), 512, 0, stream>>>(
        priors, shapes, starts, offattn, value, Wof, b_out, out);
}

// Round 19
// 80.407 us; speedup vs baseline: 1.1194x; 1.0032x over previous
//
#include <hip/hip_runtime.h>
#include <hip/hip_bf16.h>

// Problem constants (fixed by reference)
#define B_    4
#define Qn_   2048
#define S_    21760   // 128*128 + 64*64 + 32*32 + 16*16

typedef short  bfx4    __attribute__((ext_vector_type(4)));
typedef short  short8  __attribute__((ext_vector_type(8)));
typedef float  floatx4 __attribute__((ext_vector_type(4)));

__device__ __forceinline__ unsigned short f2bf(float f) {
    unsigned int u = __builtin_bit_cast(unsigned int, f);
    u += 0x7fffu + ((u >> 16) & 1u);   // round-to-nearest-even
    return (unsigned short)(u >> 16);
}
__device__ __forceinline__ float bf2f(unsigned short h) {
    unsigned int u = ((unsigned int)h) << 16;
    return __builtin_bit_cast(float, u);
}

// packed f32x8 -> bf16x8 via v_cvt_pk_bf16_f32 (RNE, 1 instr / 2 elems)
__device__ __forceinline__ short8 cvt_pk8(floatx4 f0, floatx4 f1) {
    union { unsigned int u[4]; short8 s; } r;
    asm("v_cvt_pk_bf16_f32 %0, %1, %2" : "=v"(r.u[0]) : "v"(f0[0]), "v"(f0[1]));
    asm("v_cvt_pk_bf16_f32 %0, %1, %2" : "=v"(r.u[1]) : "v"(f0[2]), "v"(f0[3]));
    asm("v_cvt_pk_bf16_f32 %0, %1, %2" : "=v"(r.u[2]) : "v"(f1[0]), "v"(f1[1]));
    asm("v_cvt_pk_bf16_f32 %0, %1, %2" : "=v"(r.u[3]) : "v"(f1[2]), "v"(f1[3]));
    return r.s;
}

template<int N>
__device__ __forceinline__ void wait_vm_lgkm0() {
    asm volatile("s_waitcnt vmcnt(%0) lgkmcnt(0)" :: "n"(N) : "memory");
}

// ---------------------------------------------------------------------------
// prep_all: ONE dispatch for all weight prep (r15 verified).
// ---------------------------------------------------------------------------
__global__ __launch_bounds__(1024) void prep_all(
        const float* __restrict__ Wv, const float* __restrict__ Wo,
        const float* __restrict__ Woff, const float* __restrict__ Wattn,
        const float* __restrict__ boff, const float* __restrict__ battn,
        short* __restrict__ Wvt, short* __restrict__ Wcat,
        short* __restrict__ Wof, float* __restrict__ bcat) {
    const int bid = blockIdx.x;
    const int t   = threadIdx.x;
    if (bid < 256) {
        const int k = bid;
        if (t < 256) {
            Wvt[t * 256 + k] = (short)f2bf(Wv[k * 256 + t]);
        } else if (t < 640) {
            const int n = t - 256;     // 0..383
            const float w = (n < 256) ? Woff[k * 256 + n] : Wattn[k * 128 + (n - 256)];
            Wcat[n * 256 + k] = (short)f2bf(w);
        }
        if (bid == 0 && t < 384)
            bcat[t] = (t < 256) ? boff[t] : battn[t - 256];
    } else {
        const int g = (bid - 256) * 1024 + t;   // 0..65535
        const int j  = g & 7;
        const int l  = (g >> 3) & 63;
        const int nf = (g >> 9) & 15;
        const int kc = g >> 13;
        const int k = kc * 32 + (l >> 4) * 8 + j;
        const int n = nf * 16 + (l & 15);
        Wof[g] = (short)f2bf(Wo[k * 256 + n]);
    }
}

// ---------------------------------------------------------------------------
// gemm_core: r18 structure with B staging switched from global_load_lds DMA
//   to T14 REG-STAGING (buffer_load->reg->swizzled ds_write), testing the
//   "LDS-DMA path throughput cap" hypothesis.  BM=64, BN=NF*64, 4 waves.
//   Per step: loadB(k+1) issued FIRST (latency hides under compute),
//   loadA(k+2) 2-ahead, compute(cur), writeA(k+1) cvt_pk, writeB(k+1),
//   wait vmcnt(2)[A(k+2) stays in flight] lgkmcnt(0), barrier.
//   Swizzle (rule #21 both-sides): LDS chunk col*4 + (ch^(col&3)) holds
//   G[col][ch]; read at chunk r*4+(lq^(r&3)) yields G[r][lq]  -- verified.
// ---------------------------------------------------------------------------
template<int NF, int OUT_F32>
__device__ __forceinline__ void gemm_core(
        const float* __restrict__ Av, const short* __restrict__ Bt,
        const float* __restrict__ bias, void* __restrict__ Cv,
        long row0, int Ntot, int colbase,
        short (&As)[2][2048], short (&Bs)[2][8192]) {
    const int tid  = threadIdx.x;
    const int lane = tid & 63, wave = tid >> 6;
    const int l16  = lane & 15, lq = lane >> 4;
    const int r_a = tid >> 2, c_a = tid & 3;

    floatx4 sA0[2], sA1[2];
    short8  sB[NF];

    auto loadA = [&](int kk, int s) {
        const float* g = Av + (row0 + r_a) * 256 + kk * 32 + c_a * 8;
        sA0[s] = *(const floatx4*)g;
        sA1[s] = *(const floatx4*)(g + 4);
    };
    auto writeA = [&](int buf, int s) {
        *(short8*)&As[buf][r_a * 32 + ((c_a ^ (r_a & 3)) << 3)] = cvt_pk8(sA0[s], sA1[s]);
    };
    auto loadB = [&](int kk) {                // linear source reads
#pragma unroll
        for (int c2 = 0; c2 < NF; ++c2) {
            const int idx = c2 * 256 + tid;
            const int col = idx >> 2, ch = idx & 3;
            sB[c2] = *(const short8*)(Bt + (long)col * 256 + kk * 32 + ch * 8);
        }
    };
    auto writeB = [&](int buf) {              // swizzled ds_write dest
#pragma unroll
        for (int c2 = 0; c2 < NF; ++c2) {
            const int idx = c2 * 256 + tid;
            const int col = idx >> 2, ch = idx & 3;
            *(short8*)&Bs[buf][col * 32 + ((ch ^ (col & 3)) << 3)] = sB[c2];
        }
    };

    floatx4 acc[4][NF];
#pragma unroll
    for (int i = 0; i < 4; ++i)
#pragma unroll
        for (int j = 0; j < NF; ++j) acc[i][j] = (floatx4){0.f, 0.f, 0.f, 0.f};

    auto compute = [&](int buf) {
        short8 af[4], bv[NF];
#pragma unroll
        for (int mf = 0; mf < 4; ++mf) {
            const int r = mf * 16 + l16;
            af[mf] = *(const short8*)&As[buf][r * 32 + ((lq ^ (r & 3)) << 3)];
        }
#pragma unroll
        for (int nf = 0; nf < NF; ++nf) {
            const int r = wave * (NF * 16) + nf * 16 + l16;
            bv[nf] = *(const short8*)&Bs[buf][r * 32 + ((lq ^ (r & 3)) << 3)];
        }
#pragma unroll
        for (int mf = 0; mf < 4; ++mf)
#pragma unroll
            for (int nf = 0; nf < NF; ++nf)
                acc[mf][nf] = __builtin_amdgcn_mfma_f32_16x16x32_bf16(
                    bv[nf], af[mf], acc[mf][nf], 0, 0, 0);   // swapped -> row-major D
    };

    // --- prologue ---
    loadB(0);
    loadA(0, 0);
    loadA(1, 1);
    writeB(0);                 // compiler waits B(0) loads
    writeA(0, 0);              // compiler waits A(0) loads; A(1) stays in flight
    wait_vm_lgkm0<2>();
    __builtin_amdgcn_s_barrier();
    __builtin_amdgcn_sched_barrier(0);

    // --- K loop ---
#pragma unroll
    for (int k = 0; k < 7; ++k) {
        const int cur = k & 1, nxt = cur ^ 1;
        loadB(k + 1);                          // issued first: hides under compute
        if (k < 6) loadA(k + 2, k & 1);        // 2-step-ahead A prefetch
        compute(cur);
        writeA(nxt, (k + 1) & 1);              // waits A(k+1) (landed long ago)
        writeB(nxt);                           // waits B(k+1) (hidden by compute)
        if (k < 6) wait_vm_lgkm0<2>();         // keep A(k+2) in flight
        else       wait_vm_lgkm0<0>();
        __builtin_amdgcn_s_barrier();
        __builtin_amdgcn_sched_barrier(0);
    }
    compute(1);

    // --- epilogue: row-major stores ---
#pragma unroll
    for (int mf = 0; mf < 4; ++mf) {
        const long grow = row0 + mf * 16 + l16;
#pragma unroll
        for (int nf = 0; nf < NF; ++nf) {
            const int gcol = colbase + wave * (NF * 16) + nf * 16 + lq * 4;
            const floatx4 bv4 = *(const floatx4*)(bias + gcol);
            const floatx4 v = acc[mf][nf] + bv4;
            if (OUT_F32) {
                *(floatx4*)((float*)Cv + grow * Ntot + gcol) = v;
            } else {
                bfx4 s;
#pragma unroll
                for (int r = 0; r < 4; ++r) s[r] = (short)f2bf(v[r]);
                *(bfx4*)((short*)Cv + grow * Ntot + gcol) = s;
            }
        }
    }
}

// ---------------------------------------------------------------------------
// gemm_mega: value + offattn GEMMs fused (block classes), value FIRST.
//   Blocks [0,1360): value tiles                 (core<4,0>, A=sfeats)
//   Blocks [1360,1488): off cols 0..255          (core<4,1>, A=in_feats)
//   Blocks [1488,1616): attn cols 256..383       (core<2,1>, A=in_feats)
// ---------------------------------------------------------------------------
__global__ __launch_bounds__(256, 4) void gemm_mega(
        const float* __restrict__ sfeats, const float* __restrict__ in_feats,
        const short* __restrict__ Wvt, const short* __restrict__ Wcat,
        const float* __restrict__ b_val, const float* __restrict__ bcat,
        short* __restrict__ value, float* __restrict__ offattn) {
    __shared__ short As[2][2048];    // 8 KB
    __shared__ short Bs[2][8192];    // 32 KB

    const int bid = blockIdx.x;
    const int nval = (B_ * S_) / 64;                 // 1360
    if (bid < nval) {
        gemm_core<4, 0>(sfeats, Wvt, b_val, (void*)value,
                        (long)bid * 64, 256, 0, As, Bs);
    } else if (bid < nval + 128) {
        gemm_core<4, 1>(in_feats, Wcat, bcat, (void*)offattn,
                        (long)(bid - nval) * 64, 384, 0, As, Bs);
    } else {
        gemm_core<2, 1>(in_feats, Wcat + 65536, bcat, (void*)offattn,
                        (long)(bid - nval - 128) * 64, 384, 256, As, Bs);
    }
}

// ---------------------------------------------------------------------------
// sampler_out: softmax + deformable gather + OUT GEMM fused (r18 verified,
//   wave-parallel softmax).
// ---------------------------------------------------------------------------
__global__ __launch_bounds__(512) void sampler_out(
        const float* __restrict__ priors,
        const int* __restrict__ shapes, const int* __restrict__ starts,
        const float* __restrict__ offattn,
        const short* __restrict__ value,
        const short* __restrict__ Wof, const float* __restrict__ b_out,
        float* __restrict__ out) {
    __shared__ float oa_lds[16][384];
    __shared__ short wv_lds[16][256];   // 8 KB, chunk c stored at c^(row&7)
    __shared__ float pri_lds[16][4][2];
    __shared__ int   shp_lds[4][2];
    __shared__ int   st_lds[4];

    const int tid = threadIdx.x;
    const int b   = blockIdx.x >> 7;
    const int qt  = blockIdx.x & 127;
    const long q0 = (long)qt * 16;

    const float* src = offattn + ((long)b * Qn_ + q0) * 384;
    for (int i = tid; i < 16 * 384 / 4; i += 512)
        ((floatx4*)oa_lds)[i] = ((const floatx4*)src)[i];
    if (tid < 128) ((float*)pri_lds)[tid] = priors[((long)b * Qn_ + q0) * 8 + tid];
    if (tid < 8)  ((int*)shp_lds)[tid] = shapes[tid];
    if (tid < 4)  st_lds[tid] = starts[tid];
    __syncthreads();

    // ---- wave-parallel softmax: 4 lanes per (qi,h) row of 16 logits ----
    {
        const int pair = tid >> 2;            // 0..127 -> (qi, h)
        const int qi = pair >> 3, h = pair & 7;
        const int quarter = tid & 3;
        float* ap = &oa_lds[qi][256 + h * 16 + quarter * 4];
        floatx4 a = *(floatx4*)ap;
        float m = fmaxf(fmaxf(a[0], a[1]), fmaxf(a[2], a[3]));
        m = fmaxf(m, __shfl_xor(m, 1));
        m = fmaxf(m, __shfl_xor(m, 2));
        floatx4 e;
#pragma unroll
        for (int i = 0; i < 4; ++i) e[i] = expf(a[i] - m);
        float s = e[0] + e[1] + e[2] + e[3];
        s += __shfl_xor(s, 1);
        s += __shfl_xor(s, 2);
        const float inv = 1.f / s;
#pragma unroll
        for (int i = 0; i < 4; ++i) e[i] *= inv;
        *(floatx4*)ap = e;
    }
    __syncthreads();

    // ---- sampling: thread (qi, h, sub) -> 8 channels; wv -> LDS ----
    {
        const int pairi = tid >> 2, sub = tid & 3;
        const int qi = pairi >> 3, h = pairi & 7;
        float acc[8];
#pragma unroll
        for (int j = 0; j < 8; ++j) acc[j] = 0.f;
        const short* vbase = value + (long)b * S_ * 256 + h * 32 + sub * 8;

        for (int l = 0; l < 4; ++l) {
            const int Hl = shp_lds[l][0], Wl = shp_lds[l][1];
            const int st = st_lds[l];
            const float px = pri_lds[qi][l][0], py = pri_lds[qi][l][1];
            const float invW = 1.f / (float)Wl, invH = 1.f / (float)Hl;

            float wgt[16];
            int   off[16];
#pragma unroll
            for (int p = 0; p < 4; ++p) {
                const int cb = h * 16 + l * 4 + p;
                const float ox = oa_lds[qi][cb * 2], oy = oa_lds[qi][cb * 2 + 1];
                const float lx = px + ox * invW, ly = py + oy * invH;
                const float ix = lx * (float)Wl - 0.5f, iy = ly * (float)Hl - 0.5f;
                const float x0f = floorf(ix), y0f = floorf(iy);
                const int x0 = (int)x0f, y0 = (int)y0f;
                const float fx = ix - x0f, fy = iy - y0f;
                const float awv = oa_lds[qi][256 + cb];
#pragma unroll
                for (int dy = 0; dy < 2; ++dy) {
                    const int yc = y0 + dy;
                    const float wy = dy ? fy : 1.f - fy;
                    const int yi = min(max(yc, 0), Hl - 1);
#pragma unroll
                    for (int dx = 0; dx < 2; ++dx) {
                        const int xc = x0 + dx;
                        const float wx = dx ? fx : 1.f - fx;
                        const int xi = min(max(xc, 0), Wl - 1);
                        const bool v = (xc >= 0) & (xc < Wl) & (yc >= 0) & (yc < Hl);
                        const int j = p * 4 + dy * 2 + dx;
                        wgt[j] = v ? wy * wx * awv : 0.f;
                        off[j] = yi * Wl + xi;
                    }
                }
            }
            const short* base = vbase + (long)st * 256;
            short8 vv[16];
#pragma unroll
            for (int j = 0; j < 16; ++j)
                vv[j] = *(const short8*)(base + (long)off[j] * 256);
#pragma unroll
            for (int j = 0; j < 16; ++j) {
                const float w = wgt[j];
#pragma unroll
                for (int c = 0; c < 8; ++c) acc[c] += w * bf2f((unsigned short)vv[j][c]);
            }
        }

        short8 ov;
#pragma unroll
        for (int j = 0; j < 8; ++j) ov[j] = (short)f2bf(acc[j]);
        const int chunk = (h * 4 + sub) ^ (qi & 7);       // XOR swizzle
        *(short8*)&wv_lds[qi][chunk * 8] = ov;
    }
    __syncthreads();

    // ---- out GEMM: wave w -> cols w*32 .. +31 (16 reg-operand MFMAs) ----
    {
        const int lane = tid & 63, w = tid >> 6;
        const int l16 = lane & 15, lq = lane >> 4;

        short8 bfrag[8][2];
#pragma unroll
        for (int kc = 0; kc < 8; ++kc)
#pragma unroll
            for (int nf = 0; nf < 2; ++nf)
                bfrag[kc][nf] = *(const short8*)(
                    Wof + (long)((kc * 16 + w * 2 + nf) * 64 + lane) * 8);

        short8 af[8];
#pragma unroll
        for (int kc = 0; kc < 8; ++kc) {
            const int chunk = (kc * 4 + lq) ^ (l16 & 7);
            af[kc] = *(const short8*)&wv_lds[l16][chunk * 8];
        }

        floatx4 acc2[2];
#pragma unroll
        for (int nf = 0; nf < 2; ++nf) acc2[nf] = (floatx4){0.f, 0.f, 0.f, 0.f};
#pragma unroll
        for (int kc = 0; kc < 8; ++kc)
#pragma unroll
            for (int nf = 0; nf < 2; ++nf)
                acc2[nf] = __builtin_amdgcn_mfma_f32_16x16x32_bf16(
                    bfrag[kc][nf], af[kc], acc2[nf], 0, 0, 0);  // swapped -> row-major

        float* co = out + ((long)b * Qn_ + q0 + l16) * 256 + w * 32 + lq * 4;
#pragma unroll
        for (int nf = 0; nf < 2; ++nf) {
            const floatx4 bv4 = *(const floatx4*)(b_out + w * 32 + nf * 16 + lq * 4);
            *(floatx4*)(co + nf * 16) = acc2[nf] + bv4;
        }
    }
}

// ---------------------------------------------------------------------------
extern "C" void kernel_launch(void* const* d_in, const int* in_sizes, int n_in,
                              void* d_out, int out_size, void* d_ws, size_t ws_size,
                              hipStream_t stream) {
    const float* in_feats = (const float*)d_in[0];
    const float* priors   = (const float*)d_in[1];
    const float* sfeats   = (const float*)d_in[2];
    const int*   shapes   = (const int*)d_in[3];
    const int*   starts   = (const int*)d_in[4];
    const float* W_off    = (const float*)d_in[5];
    const float* b_off    = (const float*)d_in[6];
    const float* W_attn   = (const float*)d_in[7];
    const float* b_attn   = (const float*)d_in[8];
    const float* W_val    = (const float*)d_in[9];
    const float* b_val    = (const float*)d_in[10];
    const float* W_out    = (const float*)d_in[11];
    const float* b_out    = (const float*)d_in[12];
    float* out = (float*)d_out;

    // Workspace: Wvt 128K | Wof 128K | Wcat 192K | value 44.56M (short)
    //            offattn 12.58M | bcat 1.5K (f32)
    short* Wvt     = (short*)d_ws;
    short* Wof     = Wvt + 65536;
    short* Wcat    = Wof + 65536;
    short* value   = Wcat + 98304;
    float* offattn = (float*)(value + (long)B_ * S_ * 256);
    float* bcat    = offattn + (long)B_ * Qn_ * 384;

    // all weight prep in one dispatch
    prep_all<<<320, 1024, 0, stream>>>(W_val, W_out, W_off, W_attn, b_off, b_attn,
                                       Wvt, Wcat, Wof, bcat);
    // value GEMM + offattn GEMM fused (one dispatch, value blocks first)
    gemm_mega<<<256 + (B_ * S_) / 64, 256, 0, stream>>>(
        sfeats, in_feats, Wvt, Wcat, b_val, bcat, value, offattn);
    // softmax + deformable sampling + out GEMM fused
    sampler_out<<<B_ * (Qn_ / 16), 512, 0, stream>>>(
        priors, shapes, starts, offattn, value, Wof, b_out, out);
}

// Round 21
// 80.343 us; speedup vs baseline: 1.1202x; 1.0008x over previous
//
#include <hip/hip_runtime.h>
#include <hip/hip_bf16.h>

// Problem constants (fixed by reference)
#define B_    4
#define Qn_   2048
#define S_    21760   // 128*128 + 64*64 + 32*32 + 16*16

typedef short  bfx4    __attribute__((ext_vector_type(4)));
typedef short  short8  __attribute__((ext_vector_type(8)));
typedef float  floatx4 __attribute__((ext_vector_type(4)));

__device__ __forceinline__ unsigned short f2bf(float f) {
    unsigned int u = __builtin_bit_cast(unsigned int, f);
    u += 0x7fffu + ((u >> 16) & 1u);   // round-to-nearest-even
    return (unsigned short)(u >> 16);
}
__device__ __forceinline__ float bf2f(unsigned short h) {
    unsigned int u = ((unsigned int)h) << 16;
    return __builtin_bit_cast(float, u);
}

// packed f32x8 -> bf16x8 via v_cvt_pk_bf16_f32 (RNE, 1 instr / 2 elems)
__device__ __forceinline__ short8 cvt_pk8(floatx4 f0, floatx4 f1) {
    union { unsigned int u[4]; short8 s; } r;
    asm("v_cvt_pk_bf16_f32 %0, %1, %2" : "=v"(r.u[0]) : "v"(f0[0]), "v"(f0[1]));
    asm("v_cvt_pk_bf16_f32 %0, %1, %2" : "=v"(r.u[1]) : "v"(f0[2]), "v"(f0[3]));
    asm("v_cvt_pk_bf16_f32 %0, %1, %2" : "=v"(r.u[2]) : "v"(f1[0]), "v"(f1[1]));
    asm("v_cvt_pk_bf16_f32 %0, %1, %2" : "=v"(r.u[3]) : "v"(f1[2]), "v"(f1[3]));
    return r.s;
}

template<int N>
__device__ __forceinline__ void wait_vm_lgkm0() {
    asm volatile("s_waitcnt vmcnt(%0) lgkmcnt(0)" :: "n"(N) : "memory");
}

// ---------------------------------------------------------------------------
// prep_all: ONE dispatch for all weight prep (r15 verified).
// ---------------------------------------------------------------------------
__global__ __launch_bounds__(1024) void prep_all(
        const float* __restrict__ Wv, const float* __restrict__ Wo,
        const float* __restrict__ Woff, const float* __restrict__ Wattn,
        const float* __restrict__ boff, const float* __restrict__ battn,
        short* __restrict__ Wvt, short* __restrict__ Wcat,
        short* __restrict__ Wof, float* __restrict__ bcat) {
    const int bid = blockIdx.x;
    const int t   = threadIdx.x;
    if (bid < 256) {
        const int k = bid;
        if (t < 256) {
            Wvt[t * 256 + k] = (short)f2bf(Wv[k * 256 + t]);
        } else if (t < 640) {
            const int n = t - 256;     // 0..383
            const float w = (n < 256) ? Woff[k * 256 + n] : Wattn[k * 128 + (n - 256)];
            Wcat[n * 256 + k] = (short)f2bf(w);
        }
        if (bid == 0 && t < 384)
            bcat[t] = (t < 256) ? boff[t] : battn[t - 256];
    } else {
        const int g = (bid - 256) * 1024 + t;   // 0..65535
        const int j  = g & 7;
        const int l  = (g >> 3) & 63;
        const int nf = (g >> 9) & 15;
        const int kc = g >> 13;
        const int k = kc * 32 + (l >> 4) * 8 + j;
        const int n = nf * 16 + (l & 15);
        Wof[g] = (short)f2bf(Wo[k * 256 + n]);
    }
}

// ---------------------------------------------------------------------------
// gemm_core: r18 structure with B staging via T14 REG-STAGING
//   (buffer_load->reg->swizzled ds_write).  BM=64, BN=NF*64, 4 waves.
//   Per step: loadB(k+1) issued FIRST (latency hides under compute),
//   loadA(k+2) 2-ahead, compute(cur), writeA(k+1) cvt_pk, writeB(k+1),
//   wait vmcnt(2)[A(k+2) stays in flight] lgkmcnt(0), barrier.
//   Swizzle (rule #21 both-sides): LDS chunk col*4 + (ch^(col&3)) holds
//   G[col][ch]; read at chunk r*4+(lq^(r&3)) yields G[r][lq].
// ---------------------------------------------------------------------------
template<int NF, int OUT_F32>
__device__ __forceinline__ void gemm_core(
        const float* __restrict__ Av, const short* __restrict__ Bt,
        const float* __restrict__ bias, void* __restrict__ Cv,
        long row0, int Ntot, int colbase,
        short (&As)[2][2048], short (&Bs)[2][8192]) {
    const int tid  = threadIdx.x;
    const int lane = tid & 63, wave = tid >> 6;
    const int l16  = lane & 15, lq = lane >> 4;
    const int r_a = tid >> 2, c_a = tid & 3;

    floatx4 sA0[2], sA1[2];
    short8  sB[NF];

    auto loadA = [&](int kk, int s) {
        const float* g = Av + (row0 + r_a) * 256 + kk * 32 + c_a * 8;
        sA0[s] = *(const floatx4*)g;
        sA1[s] = *(const floatx4*)(g + 4);
    };
    auto writeA = [&](int buf, int s) {
        *(short8*)&As[buf][r_a * 32 + ((c_a ^ (r_a & 3)) << 3)] = cvt_pk8(sA0[s], sA1[s]);
    };
    auto loadB = [&](int kk) {                // linear source reads
#pragma unroll
        for (int c2 = 0; c2 < NF; ++c2) {
            const int idx = c2 * 256 + tid;
            const int col = idx >> 2, ch = idx & 3;
            sB[c2] = *(const short8*)(Bt + (long)col * 256 + kk * 32 + ch * 8);
        }
    };
    auto writeB = [&](int buf) {              // swizzled ds_write dest
#pragma unroll
        for (int c2 = 0; c2 < NF; ++c2) {
            const int idx = c2 * 256 + tid;
            const int col = idx >> 2, ch = idx & 3;
            *(short8*)&Bs[buf][col * 32 + ((ch ^ (col & 3)) << 3)] = sB[c2];
        }
    };

    floatx4 acc[4][NF];
#pragma unroll
    for (int i = 0; i < 4; ++i)
#pragma unroll
        for (int j = 0; j < NF; ++j) acc[i][j] = (floatx4){0.f, 0.f, 0.f, 0.f};

    auto compute = [&](int buf) {
        short8 af[4], bv[NF];
#pragma unroll
        for (int mf = 0; mf < 4; ++mf) {
            const int r = mf * 16 + l16;
            af[mf] = *(const short8*)&As[buf][r * 32 + ((lq ^ (r & 3)) << 3)];
        }
#pragma unroll
        for (int nf = 0; nf < NF; ++nf) {
            const int r = wave * (NF * 16) + nf * 16 + l16;
            bv[nf] = *(const short8*)&Bs[buf][r * 32 + ((lq ^ (r & 3)) << 3)];
        }
#pragma unroll
        for (int mf = 0; mf < 4; ++mf)
#pragma unroll
            for (int nf = 0; nf < NF; ++nf)
                acc[mf][nf] = __builtin_amdgcn_mfma_f32_16x16x32_bf16(
                    bv[nf], af[mf], acc[mf][nf], 0, 0, 0);   // swapped -> row-major D
    };

    // --- prologue ---
    loadB(0);
    loadA(0, 0);
    loadA(1, 1);
    writeB(0);                 // compiler waits B(0) loads
    writeA(0, 0);              // compiler waits A(0) loads; A(1) stays in flight
    wait_vm_lgkm0<2>();
    __builtin_amdgcn_s_barrier();
    __builtin_amdgcn_sched_barrier(0);

    // --- K loop ---
#pragma unroll
    for (int k = 0; k < 7; ++k) {
        const int cur = k & 1, nxt = cur ^ 1;
        loadB(k + 1);                          // issued first: hides under compute
        if (k < 6) loadA(k + 2, k & 1);        // 2-step-ahead A prefetch
        compute(cur);
        writeA(nxt, (k + 1) & 1);              // waits A(k+1) (landed long ago)
        writeB(nxt);                           // waits B(k+1) (hidden by compute)
        if (k < 6) wait_vm_lgkm0<2>();         // keep A(k+2) in flight
        else       wait_vm_lgkm0<0>();
        __builtin_amdgcn_s_barrier();
        __builtin_amdgcn_sched_barrier(0);
    }
    compute(1);

    // --- epilogue: row-major stores ---
#pragma unroll
    for (int mf = 0; mf < 4; ++mf) {
        const long grow = row0 + mf * 16 + l16;
#pragma unroll
        for (int nf = 0; nf < NF; ++nf) {
            const int gcol = colbase + wave * (NF * 16) + nf * 16 + lq * 4;
            const floatx4 bv4 = *(const floatx4*)(bias + gcol);
            const floatx4 v = acc[mf][nf] + bv4;
            if (OUT_F32) {
                *(floatx4*)((float*)Cv + grow * Ntot + gcol) = v;
            } else {
                bfx4 s;
#pragma unroll
                for (int r = 0; r < 4; ++r) s[r] = (short)f2bf(v[r]);
                *(bfx4*)((short*)Cv + grow * Ntot + gcol) = s;
            }
        }
    }
}

// ---------------------------------------------------------------------------
// gemm_mega: value + offattn GEMMs fused (block classes), value FIRST.
//   Blocks [0,1360): value tiles                 (core<4,0>, A=sfeats)
//   Blocks [1360,1488): off cols 0..255          (core<4,1>, A=in_feats)
//   Blocks [1488,1616): attn cols 256..383       (core<2,1>, A=in_feats)
// ---------------------------------------------------------------------------
__global__ __launch_bounds__(256, 4) void gemm_mega(
        const float* __restrict__ sfeats, const float* __restrict__ in_feats,
        const short* __restrict__ Wvt, const short* __restrict__ Wcat,
        const float* __restrict__ b_val, const float* __restrict__ bcat,
        short* __restrict__ value, float* __restrict__ offattn) {
    __shared__ short As[2][2048];    // 8 KB
    __shared__ short Bs[2][8192];    // 32 KB

    const int bid = blockIdx.x;
    const int nval = (B_ * S_) / 64;                 // 1360
    if (bid < nval) {
        gemm_core<4, 0>(sfeats, Wvt, b_val, (void*)value,
                        (long)bid * 64, 256, 0, As, Bs);
    } else if (bid < nval + 128) {
        gemm_core<4, 1>(in_feats, Wcat, bcat, (void*)offattn,
                        (long)(bid - nval) * 64, 384, 0, As, Bs);
    } else {
        gemm_core<2, 1>(in_feats, Wcat + 65536, bcat, (void*)offattn,
                        (long)(bid - nval - 128) * 64, 384, 256, As, Bs);
    }
}

// ---------------------------------------------------------------------------
// sampler_out: softmax + deformable gather + OUT GEMM fused (r18 verified,
//   wave-parallel softmax).
// ---------------------------------------------------------------------------
__global__ __launch_bounds__(512) void sampler_out(
        const float* __restrict__ priors,
        const int* __restrict__ shapes, const int* __restrict__ starts,
        const float* __restrict__ offattn,
        const short* __restrict__ value,
        const short* __restrict__ Wof, const float* __restrict__ b_out,
        float* __restrict__ out) {
    __shared__ float oa_lds[16][384];
    __shared__ short wv_lds[16][256];   // 8 KB, chunk c stored at c^(row&7)
    __shared__ float pri_lds[16][4][2];
    __shared__ int   shp_lds[4][2];
    __shared__ int   st_lds[4];

    const int tid = threadIdx.x;
    const int b   = blockIdx.x >> 7;
    const int qt  = blockIdx.x & 127;
    const long q0 = (long)qt * 16;

    const float* src = offattn + ((long)b * Qn_ + q0) * 384;
    for (int i = tid; i < 16 * 384 / 4; i += 512)
        ((floatx4*)oa_lds)[i] = ((const floatx4*)src)[i];
    if (tid < 128) ((float*)pri_lds)[tid] = priors[((long)b * Qn_ + q0) * 8 + tid];
    if (tid < 8)  ((int*)shp_lds)[tid] = shapes[tid];
    if (tid < 4)  st_lds[tid] = starts[tid];
    __syncthreads();

    // ---- wave-parallel softmax: 4 lanes per (qi,h) row of 16 logits ----
    {
        const int pair = tid >> 2;            // 0..127 -> (qi, h)
        const int qi = pair >> 3, h = pair & 7;
        const int quarter = tid & 3;
        float* ap = &oa_lds[qi][256 + h * 16 + quarter * 4];
        floatx4 a = *(floatx4*)ap;
        float m = fmaxf(fmaxf(a[0], a[1]), fmaxf(a[2], a[3]));
        m = fmaxf(m, __shfl_xor(m, 1));
        m = fmaxf(m, __shfl_xor(m, 2));
        floatx4 e;
#pragma unroll
        for (int i = 0; i < 4; ++i) e[i] = expf(a[i] - m);
        float s = e[0] + e[1] + e[2] + e[3];
        s += __shfl_xor(s, 1);
        s += __shfl_xor(s, 2);
        const float inv = 1.f / s;
#pragma unroll
        for (int i = 0; i < 4; ++i) e[i] *= inv;
        *(floatx4*)ap = e;
    }
    __syncthreads();

    // ---- sampling: thread (qi, h, sub) -> 8 channels; wv -> LDS ----
    {
        const int pairi = tid >> 2, sub = tid & 3;
        const int qi = pairi >> 3, h = pairi & 7;
        float acc[8];
#pragma unroll
        for (int j = 0; j < 8; ++j) acc[j] = 0.f;
        const short* vbase = value + (long)b * S_ * 256 + h * 32 + sub * 8;

        for (int l = 0; l < 4; ++l) {
            const int Hl = shp_lds[l][0], Wl = shp_lds[l][1];
            const int st = st_lds[l];
            const float px = pri_lds[qi][l][0], py = pri_lds[qi][l][1];
            const float invW = 1.f / (float)Wl, invH = 1.f / (float)Hl;

            float wgt[16];
            int   off[16];
#pragma unroll
            for (int p = 0; p < 4; ++p) {
                const int cb = h * 16 + l * 4 + p;
                const float ox = oa_lds[qi][cb * 2], oy = oa_lds[qi][cb * 2 + 1];
                const float lx = px + ox * invW, ly = py + oy * invH;
                const float ix = lx * (float)Wl - 0.5f, iy = ly * (float)Hl - 0.5f;
                const float x0f = floorf(ix), y0f = floorf(iy);
                const int x0 = (int)x0f, y0 = (int)y0f;
                const float fx = ix - x0f, fy = iy - y0f;
                const float awv = oa_lds[qi][256 + cb];
#pragma unroll
                for (int dy = 0; dy < 2; ++dy) {
                    const int yc = y0 + dy;
                    const float wy = dy ? fy : 1.f - fy;
                    const int yi = min(max(yc, 0), Hl - 1);
#pragma unroll
                    for (int dx = 0; dx < 2; ++dx) {
                        const int xc = x0 + dx;
                        const float wx = dx ? fx : 1.f - fx;
                        const int xi = min(max(xc, 0), Wl - 1);
                        const bool v = (xc >= 0) & (xc < Wl) & (yc >= 0) & (yc < Hl);
                        const int j = p * 4 + dy * 2 + dx;
                        wgt[j] = v ? wy * wx * awv : 0.f;
                        off[j] = yi * Wl + xi;
                    }
                }
            }
            const short* base = vbase + (long)st * 256;
            short8 vv[16];
#pragma unroll
            for (int j = 0; j < 16; ++j)
                vv[j] = *(const short8*)(base + (long)off[j] * 256);
#pragma unroll
            for (int j = 0; j < 16; ++j) {
                const float w = wgt[j];
#pragma unroll
                for (int c = 0; c < 8; ++c) acc[c] += w * bf2f((unsigned short)vv[j][c]);
            }
        }

        short8 ov;
#pragma unroll
        for (int j = 0; j < 8; ++j) ov[j] = (short)f2bf(acc[j]);
        const int chunk = (h * 4 + sub) ^ (qi & 7);       // XOR swizzle
        *(short8*)&wv_lds[qi][chunk * 8] = ov;
    }
    __syncthreads();

    // ---- out GEMM: wave w -> cols w*32 .. +31 (16 reg-operand MFMAs) ----
    {
        const int lane = tid & 63, w = tid >> 6;
        const int l16 = lane & 15, lq = lane >> 4;

        short8 bfrag[8][2];
#pragma unroll
        for (int kc = 0; kc < 8; ++kc)
#pragma unroll
            for (int nf = 0; nf < 2; ++nf)
                bfrag[kc][nf] = *(const short8*)(
                    Wof + (long)((kc * 16 + w * 2 + nf) * 64 + lane) * 8);

        short8 af[8];
#pragma unroll
        for (int kc = 0; kc < 8; ++kc) {
            const int chunk = (kc * 4 + lq) ^ (l16 & 7);
            af[kc] = *(const short8*)&wv_lds[l16][chunk * 8];
        }

        floatx4 acc2[2];
#pragma unroll
        for (int nf = 0; nf < 2; ++nf) acc2[nf] = (floatx4){0.f, 0.f, 0.f, 0.f};
#pragma unroll
        for (int kc = 0; kc < 8; ++kc)
#pragma unroll
            for (int nf = 0; nf < 2; ++nf)
                acc2[nf] = __builtin_amdgcn_mfma_f32_16x16x32_bf16(
                    bfrag[kc][nf], af[kc], acc2[nf], 0, 0, 0);  // swapped -> row-major

        float* co = out + ((long)b * Qn_ + q0 + l16) * 256 + w * 32 + lq * 4;
#pragma unroll
        for (int nf = 0; nf < 2; ++nf) {
            const floatx4 bv4 = *(const floatx4*)(b_out + w * 32 + nf * 16 + lq * 4);
            *(floatx4*)(co + nf * 16) = acc2[nf] + bv4;
        }
    }
}

// ---------------------------------------------------------------------------
extern "C" void kernel_launch(void* const* d_in, const int* in_sizes, int n_in,
                              void* d_out, int out_size, void* d_ws, size_t ws_size,
                              hipStream_t stream) {
    const float* in_feats = (const float*)d_in[0];
    const float* priors   = (const float*)d_in[1];
    const float* sfeats   = (const float*)d_in[2];
    const int*   shapes   = (const int*)d_in[3];
    const int*   starts   = (const int*)d_in[4];
    const float* W_off    = (const float*)d_in[5];
    const float* b_off    = (const float*)d_in[6];
    const float* W_attn   = (const float*)d_in[7];
    const float* b_attn   = (const float*)d_in[8];
    const float* W_val    = (const float*)d_in[9];
    const float* b_val    = (const float*)d_in[10];
    const float* W_out    = (const float*)d_in[11];
    const float* b_out    = (const float*)d_in[12];
    float* out = (float*)d_out;

    // Workspace: Wvt 128K | Wof 128K | Wcat 192K | value 44.56M (short)
    //            offattn 12.58M | bcat 1.5K (f32)
    short* Wvt     = (short*)d_ws;
    short* Wof     = Wvt + 65536;
    short* Wcat    = Wof + 65536;
    short* value   = Wcat + 98304;
    float* offattn = (float*)(value + (long)B_ * S_ * 256);
    float* bcat    = offattn + (long)B_ * Qn_ * 384;

    // all weight prep in one dispatch
    prep_all<<<320, 1024, 0, stream>>>(W_val, W_out, W_off, W_attn, b_off, b_attn,
                                       Wvt, Wcat, Wof, bcat);
    // value GEMM + offattn GEMM fused (one dispatch, value blocks first)
    gemm_mega<<<256 + (B_ * S_) / 64, 256, 0, stream>>>(
        sfeats, in_feats, Wvt, Wcat, b_val, bcat, value, offattn);
    // softmax + deformable sampling + out GEMM fused
    sampler_out<<<B_ * (Qn_ / 16), 512, 0, stream>>>(
        priors, shapes, starts, offattn, value, Wof, b_out, out);
}

// Round 22
// 74.804 us; speedup vs baseline: 1.2032x; 1.0740x over previous
//
#include <hip/hip_runtime.h>
#include <hip/hip_bf16.h>

// Problem constants (fixed by reference)
#define B_    4
#define Qn_   2048
#define S_    21760   // 128*128 + 64*64 + 32*32 + 16*16
#define BS_   (B_ * S_)

typedef short  bfx4    __attribute__((ext_vector_type(4)));
typedef short  short8  __attribute__((ext_vector_type(8)));
typedef float  floatx4 __attribute__((ext_vector_type(4)));

__device__ __forceinline__ unsigned short f2bf(float f) {
    unsigned int u = __builtin_bit_cast(unsigned int, f);
    u += 0x7fffu + ((u >> 16) & 1u);   // round-to-nearest-even
    return (unsigned short)(u >> 16);
}
__device__ __forceinline__ float bf2f(unsigned short h) {
    unsigned int u = ((unsigned int)h) << 16;
    return __builtin_bit_cast(float, u);
}

// packed f32x8 -> bf16x8 via v_cvt_pk_bf16_f32 (RNE, 1 instr / 2 elems)
__device__ __forceinline__ short8 cvt_pk8(floatx4 f0, floatx4 f1) {
    union { unsigned int u[4]; short8 s; } r;
    asm("v_cvt_pk_bf16_f32 %0, %1, %2" : "=v"(r.u[0]) : "v"(f0[0]), "v"(f0[1]));
    asm("v_cvt_pk_bf16_f32 %0, %1, %2" : "=v"(r.u[1]) : "v"(f0[2]), "v"(f0[3]));
    asm("v_cvt_pk_bf16_f32 %0, %1, %2" : "=v"(r.u[2]) : "v"(f1[0]), "v"(f1[1]));
    asm("v_cvt_pk_bf16_f32 %0, %1, %2" : "=v"(r.u[3]) : "v"(f1[2]), "v"(f1[3]));
    return r.s;
}

template<int N>
__device__ __forceinline__ void wait_vm_lgkm0() {
    asm volatile("s_waitcnt vmcnt(%0) lgkmcnt(0)" :: "n"(N) : "memory");
}

// ---------------------------------------------------------------------------
// prep_all: ONE dispatch for all weight prep (r15 verified).
// ---------------------------------------------------------------------------
__global__ __launch_bounds__(1024) void prep_all(
        const float* __restrict__ Wv, const float* __restrict__ Wo,
        const float* __restrict__ Woff, const float* __restrict__ Wattn,
        const float* __restrict__ boff, const float* __restrict__ battn,
        short* __restrict__ Wvt, short* __restrict__ Wcat,
        short* __restrict__ Wof, float* __restrict__ bcat) {
    const int bid = blockIdx.x;
    const int t   = threadIdx.x;
    if (bid < 256) {
        const int k = bid;
        if (t < 256) {
            Wvt[t * 256 + k] = (short)f2bf(Wv[k * 256 + t]);
        } else if (t < 640) {
            const int n = t - 256;     // 0..383
            const float w = (n < 256) ? Woff[k * 256 + n] : Wattn[k * 128 + (n - 256)];
            Wcat[n * 256 + k] = (short)f2bf(w);
        }
        if (bid == 0 && t < 384)
            bcat[t] = (t < 256) ? boff[t] : battn[t - 256];
    } else {
        const int g = (bid - 256) * 1024 + t;   // 0..65535
        const int j  = g & 7;
        const int l  = (g >> 3) & 63;
        const int nf = (g >> 9) & 15;
        const int kc = g >> 13;
        const int k = kc * 32 + (l >> 4) * 8 + j;
        const int n = nf * 16 + (l & 15);
        Wof[g] = (short)f2bf(Wo[k * 256 + n]);
    }
}

// ---------------------------------------------------------------------------
// gemm_core: r19-verified structure (T14 reg-staged B).  BM=64, BN=NF*64,
//   4 waves, 2-phase K-loop, counted vmcnt(2).
//   r22: PLANE flag -- value output stored head-plane [H][B*S][32]:
//   addr = ((gcol>>5)*BS_ + grow)*32 + (gcol&31)  (bfx4 never straddles a
//   32-col head boundary since gcol is 4-aligned and spans 4 elems).
// ---------------------------------------------------------------------------
template<int NF, int OUT_F32, int PLANE>
__device__ __forceinline__ void gemm_core(
        const float* __restrict__ Av, const short* __restrict__ Bt,
        const float* __restrict__ bias, void* __restrict__ Cv,
        long row0, int Ntot, int colbase,
        short (&As)[2][2048], short (&Bs)[2][8192]) {
    const int tid  = threadIdx.x;
    const int lane = tid & 63, wave = tid >> 6;
    const int l16  = lane & 15, lq = lane >> 4;
    const int r_a = tid >> 2, c_a = tid & 3;

    floatx4 sA0[2], sA1[2];
    short8  sB[NF];

    auto loadA = [&](int kk, int s) {
        const float* g = Av + (row0 + r_a) * 256 + kk * 32 + c_a * 8;
        sA0[s] = *(const floatx4*)g;
        sA1[s] = *(const floatx4*)(g + 4);
    };
    auto writeA = [&](int buf, int s) {
        *(short8*)&As[buf][r_a * 32 + ((c_a ^ (r_a & 3)) << 3)] = cvt_pk8(sA0[s], sA1[s]);
    };
    auto loadB = [&](int kk) {                // linear source reads
#pragma unroll
        for (int c2 = 0; c2 < NF; ++c2) {
            const int idx = c2 * 256 + tid;
            const int col = idx >> 2, ch = idx & 3;
            sB[c2] = *(const short8*)(Bt + (long)col * 256 + kk * 32 + ch * 8);
        }
    };
    auto writeB = [&](int buf) {              // swizzled ds_write dest
#pragma unroll
        for (int c2 = 0; c2 < NF; ++c2) {
            const int idx = c2 * 256 + tid;
            const int col = idx >> 2, ch = idx & 3;
            *(short8*)&Bs[buf][col * 32 + ((ch ^ (col & 3)) << 3)] = sB[c2];
        }
    };

    floatx4 acc[4][NF];
#pragma unroll
    for (int i = 0; i < 4; ++i)
#pragma unroll
        for (int j = 0; j < NF; ++j) acc[i][j] = (floatx4){0.f, 0.f, 0.f, 0.f};

    auto compute = [&](int buf) {
        short8 af[4], bv[NF];
#pragma unroll
        for (int mf = 0; mf < 4; ++mf) {
            const int r = mf * 16 + l16;
            af[mf] = *(const short8*)&As[buf][r * 32 + ((lq ^ (r & 3)) << 3)];
        }
#pragma unroll
        for (int nf = 0; nf < NF; ++nf) {
            const int r = wave * (NF * 16) + nf * 16 + l16;
            bv[nf] = *(const short8*)&Bs[buf][r * 32 + ((lq ^ (r & 3)) << 3)];
        }
#pragma unroll
        for (int mf = 0; mf < 4; ++mf)
#pragma unroll
            for (int nf = 0; nf < NF; ++nf)
                acc[mf][nf] = __builtin_amdgcn_mfma_f32_16x16x32_bf16(
                    bv[nf], af[mf], acc[mf][nf], 0, 0, 0);   // swapped -> row-major D
    };

    // --- prologue ---
    loadB(0);
    loadA(0, 0);
    loadA(1, 1);
    writeB(0);                 // compiler waits B(0) loads
    writeA(0, 0);              // compiler waits A(0) loads; A(1) stays in flight
    wait_vm_lgkm0<2>();
    __builtin_amdgcn_s_barrier();
    __builtin_amdgcn_sched_barrier(0);

    // --- K loop ---
#pragma unroll
    for (int k = 0; k < 7; ++k) {
        const int cur = k & 1, nxt = cur ^ 1;
        loadB(k + 1);                          // issued first: hides under compute
        if (k < 6) loadA(k + 2, k & 1);        // 2-step-ahead A prefetch
        compute(cur);
        writeA(nxt, (k + 1) & 1);              // waits A(k+1) (landed long ago)
        writeB(nxt);                           // waits B(k+1) (hidden by compute)
        if (k < 6) wait_vm_lgkm0<2>();         // keep A(k+2) in flight
        else       wait_vm_lgkm0<0>();
        __builtin_amdgcn_s_barrier();
        __builtin_amdgcn_sched_barrier(0);
    }
    compute(1);

    // --- epilogue: row-major stores ---
#pragma unroll
    for (int mf = 0; mf < 4; ++mf) {
        const long grow = row0 + mf * 16 + l16;
#pragma unroll
        for (int nf = 0; nf < NF; ++nf) {
            const int gcol = colbase + wave * (NF * 16) + nf * 16 + lq * 4;
            const floatx4 bv4 = *(const floatx4*)(bias + gcol);
            const floatx4 v = acc[mf][nf] + bv4;
            if (OUT_F32) {
                *(floatx4*)((float*)Cv + grow * Ntot + gcol) = v;
            } else {
                bfx4 s;
#pragma unroll
                for (int r = 0; r < 4; ++r) s[r] = (short)f2bf(v[r]);
                if (PLANE) {   // head-plane [H][B*S][32]
                    *(bfx4*)((short*)Cv + ((long)(gcol >> 5) * BS_ + grow) * 32 + (gcol & 31)) = s;
                } else {
                    *(bfx4*)((short*)Cv + grow * Ntot + gcol) = s;
                }
            }
        }
    }
}

// ---------------------------------------------------------------------------
// gemm_mega: value + offattn GEMMs fused (block classes), value FIRST.
//   Blocks [0,1360): value tiles  (core<4,0,PLANE=1>, A=sfeats)
//   Blocks [1360,1488): off cols 0..255          (core<4,1,0>, A=in_feats)
//   Blocks [1488,1616): attn cols 256..383       (core<2,1,0>, A=in_feats)
// ---------------------------------------------------------------------------
__global__ __launch_bounds__(256, 4) void gemm_mega(
        const float* __restrict__ sfeats, const float* __restrict__ in_feats,
        const short* __restrict__ Wvt, const short* __restrict__ Wcat,
        const float* __restrict__ b_val, const float* __restrict__ bcat,
        short* __restrict__ value, float* __restrict__ offattn) {
    __shared__ short As[2][2048];    // 8 KB
    __shared__ short Bs[2][8192];    // 32 KB

    const int bid = blockIdx.x;
    const int nval = (B_ * S_) / 64;                 // 1360
    if (bid < nval) {
        gemm_core<4, 0, 1>(sfeats, Wvt, b_val, (void*)value,
                           (long)bid * 64, 256, 0, As, Bs);
    } else if (bid < nval + 128) {
        gemm_core<4, 1, 0>(in_feats, Wcat, bcat, (void*)offattn,
                           (long)(bid - nval) * 64, 384, 0, As, Bs);
    } else {
        gemm_core<2, 1, 0>(in_feats, Wcat + 65536, bcat, (void*)offattn,
                           (long)(bid - nval - 128) * 64, 384, 256, As, Bs);
    }
}

// ---------------------------------------------------------------------------
// sampler_out: softmax + deformable gather + OUT GEMM fused.
//   r22: value read head-plane [H][B*S][32] -- x-adjacent bilinear corners
//   are adjacent 64B sectors (one 128B line) instead of 512B apart.
// ---------------------------------------------------------------------------
__global__ __launch_bounds__(512) void sampler_out(
        const float* __restrict__ priors,
        const int* __restrict__ shapes, const int* __restrict__ starts,
        const float* __restrict__ offattn,
        const short* __restrict__ value,
        const short* __restrict__ Wof, const float* __restrict__ b_out,
        float* __restrict__ out) {
    __shared__ float oa_lds[16][384];
    __shared__ short wv_lds[16][256];   // 8 KB, chunk c stored at c^(row&7)
    __shared__ float pri_lds[16][4][2];
    __shared__ int   shp_lds[4][2];
    __shared__ int   st_lds[4];

    const int tid = threadIdx.x;
    const int b   = blockIdx.x >> 7;
    const int qt  = blockIdx.x & 127;
    const long q0 = (long)qt * 16;

    const float* src = offattn + ((long)b * Qn_ + q0) * 384;
    for (int i = tid; i < 16 * 384 / 4; i += 512)
        ((floatx4*)oa_lds)[i] = ((const floatx4*)src)[i];
    if (tid < 128) ((float*)pri_lds)[tid] = priors[((long)b * Qn_ + q0) * 8 + tid];
    if (tid < 8)  ((int*)shp_lds)[tid] = shapes[tid];
    if (tid < 4)  st_lds[tid] = starts[tid];
    __syncthreads();

    // ---- wave-parallel softmax: 4 lanes per (qi,h) row of 16 logits ----
    {
        const int pair = tid >> 2;            // 0..127 -> (qi, h)
        const int qi = pair >> 3, h = pair & 7;
        const int quarter = tid & 3;
        float* ap = &oa_lds[qi][256 + h * 16 + quarter * 4];
        floatx4 a = *(floatx4*)ap;
        float m = fmaxf(fmaxf(a[0], a[1]), fmaxf(a[2], a[3]));
        m = fmaxf(m, __shfl_xor(m, 1));
        m = fmaxf(m, __shfl_xor(m, 2));
        floatx4 e;
#pragma unroll
        for (int i = 0; i < 4; ++i) e[i] = expf(a[i] - m);
        float s = e[0] + e[1] + e[2] + e[3];
        s += __shfl_xor(s, 1);
        s += __shfl_xor(s, 2);
        const float inv = 1.f / s;
#pragma unroll
        for (int i = 0; i < 4; ++i) e[i] *= inv;
        *(floatx4*)ap = e;
    }
    __syncthreads();

    // ---- sampling: thread (qi, h, sub) -> 8 channels; wv -> LDS ----
    {
        const int pairi = tid >> 2, sub = tid & 3;
        const int qi = pairi >> 3, h = pairi & 7;
        float acc[8];
#pragma unroll
        for (int j = 0; j < 8; ++j) acc[j] = 0.f;
        // head-plane: value[h][b*S + s][32]
        const short* vbase = value + (long)h * BS_ * 32 + (long)b * S_ * 32 + sub * 8;

        for (int l = 0; l < 4; ++l) {
            const int Hl = shp_lds[l][0], Wl = shp_lds[l][1];
            const int st = st_lds[l];
            const float px = pri_lds[qi][l][0], py = pri_lds[qi][l][1];
            const float invW = 1.f / (float)Wl, invH = 1.f / (float)Hl;

            float wgt[16];
            int   off[16];
#pragma unroll
            for (int p = 0; p < 4; ++p) {
                const int cb = h * 16 + l * 4 + p;
                const float ox = oa_lds[qi][cb * 2], oy = oa_lds[qi][cb * 2 + 1];
                const float lx = px + ox * invW, ly = py + oy * invH;
                const float ix = lx * (float)Wl - 0.5f, iy = ly * (float)Hl - 0.5f;
                const float x0f = floorf(ix), y0f = floorf(iy);
                const int x0 = (int)x0f, y0 = (int)y0f;
                const float fx = ix - x0f, fy = iy - y0f;
                const float awv = oa_lds[qi][256 + cb];
#pragma unroll
                for (int dy = 0; dy < 2; ++dy) {
                    const int yc = y0 + dy;
                    const float wy = dy ? fy : 1.f - fy;
                    const int yi = min(max(yc, 0), Hl - 1);
#pragma unroll
                    for (int dx = 0; dx < 2; ++dx) {
                        const int xc = x0 + dx;
                        const float wx = dx ? fx : 1.f - fx;
                        const int xi = min(max(xc, 0), Wl - 1);
                        const bool v = (xc >= 0) & (xc < Wl) & (yc >= 0) & (yc < Hl);
                        const int j = p * 4 + dy * 2 + dx;
                        wgt[j] = v ? wy * wx * awv : 0.f;
                        off[j] = yi * Wl + xi;
                    }
                }
            }
            const short* base = vbase + (long)st * 32;
            short8 vv[16];
#pragma unroll
            for (int j = 0; j < 16; ++j)
                vv[j] = *(const short8*)(base + (long)off[j] * 32);
#pragma unroll
            for (int j = 0; j < 16; ++j) {
                const float w = wgt[j];
#pragma unroll
                for (int c = 0; c < 8; ++c) acc[c] += w * bf2f((unsigned short)vv[j][c]);
            }
        }

        short8 ov;
#pragma unroll
        for (int j = 0; j < 8; ++j) ov[j] = (short)f2bf(acc[j]);
        const int chunk = (h * 4 + sub) ^ (qi & 7);       // XOR swizzle
        *(short8*)&wv_lds[qi][chunk * 8] = ov;
    }
    __syncthreads();

    // ---- out GEMM: wave w -> cols w*32 .. +31 (16 reg-operand MFMAs) ----
    {
        const int lane = tid & 63, w = tid >> 6;
        const int l16 = lane & 15, lq = lane >> 4;

        short8 bfrag[8][2];
#pragma unroll
        for (int kc = 0; kc < 8; ++kc)
#pragma unroll
            for (int nf = 0; nf < 2; ++nf)
                bfrag[kc][nf] = *(const short8*)(
                    Wof + (long)((kc * 16 + w * 2 + nf) * 64 + lane) * 8);

        short8 af[8];
#pragma unroll
        for (int kc = 0; kc < 8; ++kc) {
            const int chunk = (kc * 4 + lq) ^ (l16 & 7);
            af[kc] = *(const short8*)&wv_lds[l16][chunk * 8];
        }

        floatx4 acc2[2];
#pragma unroll
        for (int nf = 0; nf < 2; ++nf) acc2[nf] = (floatx4){0.f, 0.f, 0.f, 0.f};
#pragma unroll
        for (int kc = 0; kc < 8; ++kc)
#pragma unroll
            for (int nf = 0; nf < 2; ++nf)
                acc2[nf] = __builtin_amdgcn_mfma_f32_16x16x32_bf16(
                    bfrag[kc][nf], af[kc], acc2[nf], 0, 0, 0);  // swapped -> row-major

        float* co = out + ((long)b * Qn_ + q0 + l16) * 256 + w * 32 + lq * 4;
#pragma unroll
        for (int nf = 0; nf < 2; ++nf) {
            const floatx4 bv4 = *(const floatx4*)(b_out + w * 32 + nf * 16 + lq * 4);
            *(floatx4*)(co + nf * 16) = acc2[nf] + bv4;
        }
    }
}

// ---------------------------------------------------------------------------
extern "C" void kernel_launch(void* const* d_in, const int* in_sizes, int n_in,
                              void* d_out, int out_size, void* d_ws, size_t ws_size,
                              hipStream_t stream) {
    const float* in_feats = (const float*)d_in[0];
    const float* priors   = (const float*)d_in[1];
    const float* sfeats   = (const float*)d_in[2];
    const int*   shapes   = (const int*)d_in[3];
    const int*   starts   = (const int*)d_in[4];
    const float* W_off    = (const float*)d_in[5];
    const float* b_off    = (const float*)d_in[6];
    const float* W_attn   = (const float*)d_in[7];
    const float* b_attn   = (const float*)d_in[8];
    const float* W_val    = (const float*)d_in[9];
    const float* b_val    = (const float*)d_in[10];
    const float* W_out    = (const float*)d_in[11];
    const float* b_out    = (const float*)d_in[12];
    float* out = (float*)d_out;

    // Workspace: Wvt 128K | Wof 128K | Wcat 192K | value 44.56M (short)
    //            offattn 12.58M | bcat 1.5K (f32)
    short* Wvt     = (short*)d_ws;
    short* Wof     = Wvt + 65536;
    short* Wcat    = Wof + 65536;
    short* value   = Wcat + 98304;
    float* offattn = (float*)(value + (long)BS_ * 256);
    float* bcat    = offattn + (long)B_ * Qn_ * 384;

    // all weight prep in one dispatch
    prep_all<<<320, 1024, 0, stream>>>(W_val, W_out, W_off, W_attn, b_off, b_attn,
                                       Wvt, Wcat, Wof, bcat);
    // value GEMM (head-plane out) + offattn GEMM fused
    gemm_mega<<<256 + (B_ * S_) / 64, 256, 0, stream>>>(
        sfeats, in_feats, Wvt, Wcat, b_val, bcat, value, offattn);
    // softmax + deformable sampling (head-plane value) + out GEMM fused
    sampler_out<<<B_ * (Qn_ / 16), 512, 0, stream>>>(
        priors, shapes, starts, offattn, value, Wof, b_out, out);
}

// Round 23
// 74.010 us; speedup vs baseline: 1.2161x; 1.0107x over previous
//
#include <hip/hip_runtime.h>
#include <hip/hip_bf16.h>

// Problem constants (fixed by reference)
#define B_    4
#define Qn_   2048
#define S_    21760   // 128*128 + 64*64 + 32*32 + 16*16
#define BS_   (B_ * S_)

typedef short  bfx4    __attribute__((ext_vector_type(4)));
typedef short  short8  __attribute__((ext_vector_type(8)));
typedef float  floatx4 __attribute__((ext_vector_type(4)));

__device__ __forceinline__ unsigned short f2bf(float f) {
    unsigned int u = __builtin_bit_cast(unsigned int, f);
    u += 0x7fffu + ((u >> 16) & 1u);   // round-to-nearest-even
    return (unsigned short)(u >> 16);
}
__device__ __forceinline__ float bf2f(unsigned short h) {
    unsigned int u = ((unsigned int)h) << 16;
    return __builtin_bit_cast(float, u);
}

// packed f32x8 -> bf16x8 via v_cvt_pk_bf16_f32 (RNE, 1 instr / 2 elems)
__device__ __forceinline__ short8 cvt_pk8(floatx4 f0, floatx4 f1) {
    union { unsigned int u[4]; short8 s; } r;
    asm("v_cvt_pk_bf16_f32 %0, %1, %2" : "=v"(r.u[0]) : "v"(f0[0]), "v"(f0[1]));
    asm("v_cvt_pk_bf16_f32 %0, %1, %2" : "=v"(r.u[1]) : "v"(f0[2]), "v"(f0[3]));
    asm("v_cvt_pk_bf16_f32 %0, %1, %2" : "=v"(r.u[2]) : "v"(f1[0]), "v"(f1[1]));
    asm("v_cvt_pk_bf16_f32 %0, %1, %2" : "=v"(r.u[3]) : "v"(f1[2]), "v"(f1[3]));
    return r.s;
}

template<int N>
__device__ __forceinline__ void wait_vm_lgkm0() {
    asm volatile("s_waitcnt vmcnt(%0) lgkmcnt(0)" :: "n"(N) : "memory");
}

// ---------------------------------------------------------------------------
// prep_all: ONE dispatch for all weight prep (r15 verified).
// ---------------------------------------------------------------------------
__global__ __launch_bounds__(1024) void prep_all(
        const float* __restrict__ Wv, const float* __restrict__ Wo,
        const float* __restrict__ Woff, const float* __restrict__ Wattn,
        const float* __restrict__ boff, const float* __restrict__ battn,
        short* __restrict__ Wvt, short* __restrict__ Wcat,
        short* __restrict__ Wof, float* __restrict__ bcat) {
    const int bid = blockIdx.x;
    const int t   = threadIdx.x;
    if (bid < 256) {
        const int k = bid;
        if (t < 256) {
            Wvt[t * 256 + k] = (short)f2bf(Wv[k * 256 + t]);
        } else if (t < 640) {
            const int n = t - 256;     // 0..383
            const float w = (n < 256) ? Woff[k * 256 + n] : Wattn[k * 128 + (n - 256)];
            Wcat[n * 256 + k] = (short)f2bf(w);
        }
        if (bid == 0 && t < 384)
            bcat[t] = (t < 256) ? boff[t] : battn[t - 256];
    } else {
        const int g = (bid - 256) * 1024 + t;   // 0..65535
        const int j  = g & 7;
        const int l  = (g >> 3) & 63;
        const int nf = (g >> 9) & 15;
        const int kc = g >> 13;
        const int k = kc * 32 + (l >> 4) * 8 + j;
        const int n = nf * 16 + (l & 15);
        Wof[g] = (short)f2bf(Wo[k * 256 + n]);
    }
}

// ---------------------------------------------------------------------------
// gemm_core: r19-verified structure (T14 reg-staged B).  BM=64, BN=NF*64,
//   4 waves, 2-phase K-loop, counted vmcnt(2).
//   OUT_F32=1: f32 linear.  OUT_F32=0 & PLANE=0: bf16 linear.
//   OUT_F32=0 & PLANE=1: bf16 head-plane [H][B*S][32] (r22 verified).
// ---------------------------------------------------------------------------
template<int NF, int OUT_F32, int PLANE>
__device__ __forceinline__ void gemm_core(
        const float* __restrict__ Av, const short* __restrict__ Bt,
        const float* __restrict__ bias, void* __restrict__ Cv,
        long row0, int Ntot, int colbase,
        short (&As)[2][2048], short (&Bs)[2][8192]) {
    const int tid  = threadIdx.x;
    const int lane = tid & 63, wave = tid >> 6;
    const int l16  = lane & 15, lq = lane >> 4;
    const int r_a = tid >> 2, c_a = tid & 3;

    floatx4 sA0[2], sA1[2];
    short8  sB[NF];

    auto loadA = [&](int kk, int s) {
        const float* g = Av + (row0 + r_a) * 256 + kk * 32 + c_a * 8;
        sA0[s] = *(const floatx4*)g;
        sA1[s] = *(const floatx4*)(g + 4);
    };
    auto writeA = [&](int buf, int s) {
        *(short8*)&As[buf][r_a * 32 + ((c_a ^ (r_a & 3)) << 3)] = cvt_pk8(sA0[s], sA1[s]);
    };
    auto loadB = [&](int kk) {                // linear source reads
#pragma unroll
        for (int c2 = 0; c2 < NF; ++c2) {
            const int idx = c2 * 256 + tid;
            const int col = idx >> 2, ch = idx & 3;
            sB[c2] = *(const short8*)(Bt + (long)col * 256 + kk * 32 + ch * 8);
        }
    };
    auto writeB = [&](int buf) {              // swizzled ds_write dest
#pragma unroll
        for (int c2 = 0; c2 < NF; ++c2) {
            const int idx = c2 * 256 + tid;
            const int col = idx >> 2, ch = idx & 3;
            *(short8*)&Bs[buf][col * 32 + ((ch ^ (col & 3)) << 3)] = sB[c2];
        }
    };

    floatx4 acc[4][NF];
#pragma unroll
    for (int i = 0; i < 4; ++i)
#pragma unroll
        for (int j = 0; j < NF; ++j) acc[i][j] = (floatx4){0.f, 0.f, 0.f, 0.f};

    auto compute = [&](int buf) {
        short8 af[4], bv[NF];
#pragma unroll
        for (int mf = 0; mf < 4; ++mf) {
            const int r = mf * 16 + l16;
            af[mf] = *(const short8*)&As[buf][r * 32 + ((lq ^ (r & 3)) << 3)];
        }
#pragma unroll
        for (int nf = 0; nf < NF; ++nf) {
            const int r = wave * (NF * 16) + nf * 16 + l16;
            bv[nf] = *(const short8*)&Bs[buf][r * 32 + ((lq ^ (r & 3)) << 3)];
        }
#pragma unroll
        for (int mf = 0; mf < 4; ++mf)
#pragma unroll
            for (int nf = 0; nf < NF; ++nf)
                acc[mf][nf] = __builtin_amdgcn_mfma_f32_16x16x32_bf16(
                    bv[nf], af[mf], acc[mf][nf], 0, 0, 0);   // swapped -> row-major D
    };

    // --- prologue ---
    loadB(0);
    loadA(0, 0);
    loadA(1, 1);
    writeB(0);                 // compiler waits B(0) loads
    writeA(0, 0);              // compiler waits A(0) loads; A(1) stays in flight
    wait_vm_lgkm0<2>();
    __builtin_amdgcn_s_barrier();
    __builtin_amdgcn_sched_barrier(0);

    // --- K loop ---
#pragma unroll
    for (int k = 0; k < 7; ++k) {
        const int cur = k & 1, nxt = cur ^ 1;
        loadB(k + 1);                          // issued first: hides under compute
        if (k < 6) loadA(k + 2, k & 1);        // 2-step-ahead A prefetch
        compute(cur);
        writeA(nxt, (k + 1) & 1);              // waits A(k+1) (landed long ago)
        writeB(nxt);                           // waits B(k+1) (hidden by compute)
        if (k < 6) wait_vm_lgkm0<2>();         // keep A(k+2) in flight
        else       wait_vm_lgkm0<0>();
        __builtin_amdgcn_s_barrier();
        __builtin_amdgcn_sched_barrier(0);
    }
    compute(1);

    // --- epilogue: row-major stores ---
#pragma unroll
    for (int mf = 0; mf < 4; ++mf) {
        const long grow = row0 + mf * 16 + l16;
#pragma unroll
        for (int nf = 0; nf < NF; ++nf) {
            const int gcol = colbase + wave * (NF * 16) + nf * 16 + lq * 4;
            const floatx4 bv4 = *(const floatx4*)(bias + gcol);
            const floatx4 v = acc[mf][nf] + bv4;
            if (OUT_F32) {
                *(floatx4*)((float*)Cv + grow * Ntot + gcol) = v;
            } else {
                bfx4 s;
#pragma unroll
                for (int r = 0; r < 4; ++r) s[r] = (short)f2bf(v[r]);
                if (PLANE) {   // head-plane [H][B*S][32]
                    *(bfx4*)((short*)Cv + ((long)(gcol >> 5) * BS_ + grow) * 32 + (gcol & 31)) = s;
                } else {
                    *(bfx4*)((short*)Cv + grow * Ntot + gcol) = s;
                }
            }
        }
    }
}

// ---------------------------------------------------------------------------
// gemm_mega: value + offattn GEMMs fused (block classes), value FIRST.
//   Blocks [0,1360): value tiles  (core<4,0,1>, head-plane bf16, A=sfeats)
//   Blocks [1360,1488): off cols 0..255   (core<4,0,0>, bf16 linear)
//   Blocks [1488,1616): attn cols 256..383 (core<2,0,0>, bf16 linear)
// ---------------------------------------------------------------------------
__global__ __launch_bounds__(256, 4) void gemm_mega(
        const float* __restrict__ sfeats, const float* __restrict__ in_feats,
        const short* __restrict__ Wvt, const short* __restrict__ Wcat,
        const float* __restrict__ b_val, const float* __restrict__ bcat,
        short* __restrict__ value, short* __restrict__ offattn) {
    __shared__ short As[2][2048];    // 8 KB
    __shared__ short Bs[2][8192];    // 32 KB

    const int bid = blockIdx.x;
    const int nval = (B_ * S_) / 64;                 // 1360
    if (bid < nval) {
        gemm_core<4, 0, 1>(sfeats, Wvt, b_val, (void*)value,
                           (long)bid * 64, 256, 0, As, Bs);
    } else if (bid < nval + 128) {
        gemm_core<4, 0, 0>(in_feats, Wcat, bcat, (void*)offattn,
                           (long)(bid - nval) * 64, 384, 0, As, Bs);
    } else {
        gemm_core<2, 0, 0>(in_feats, Wcat + 65536, bcat, (void*)offattn,
                           (long)(bid - nval - 128) * 64, 384, 256, As, Bs);
    }
}

// ---------------------------------------------------------------------------
// sampler_out: softmax + deformable gather + OUT GEMM fused.
//   r23: offattn staged from bf16 (short8 -> f32 oa_lds); value head-plane.
// ---------------------------------------------------------------------------
__global__ __launch_bounds__(512) void sampler_out(
        const float* __restrict__ priors,
        const int* __restrict__ shapes, const int* __restrict__ starts,
        const short* __restrict__ offattn,   // bf16 [B*Q][384]
        const short* __restrict__ value,
        const short* __restrict__ Wof, const float* __restrict__ b_out,
        float* __restrict__ out) {
    __shared__ float oa_lds[16][384];
    __shared__ short wv_lds[16][256];   // 8 KB, chunk c stored at c^(row&7)
    __shared__ float pri_lds[16][4][2];
    __shared__ int   shp_lds[4][2];
    __shared__ int   st_lds[4];

    const int tid = threadIdx.x;
    const int b   = blockIdx.x >> 7;
    const int qt  = blockIdx.x & 127;
    const long q0 = (long)qt * 16;

    // stage bf16 offattn -> f32 LDS (768 short8 chunks, 8 elems each)
    const short8* src8 = (const short8*)(offattn + ((long)b * Qn_ + q0) * 384);
    float* oaf = (float*)oa_lds;
    for (int i = tid; i < 768; i += 512) {
        const short8 v = src8[i];
#pragma unroll
        for (int j = 0; j < 8; ++j) oaf[i * 8 + j] = bf2f((unsigned short)v[j]);
    }
    if (tid < 128) ((float*)pri_lds)[tid] = priors[((long)b * Qn_ + q0) * 8 + tid];
    if (tid < 8)  ((int*)shp_lds)[tid] = shapes[tid];
    if (tid < 4)  st_lds[tid] = starts[tid];
    __syncthreads();

    // ---- wave-parallel softmax: 4 lanes per (qi,h) row of 16 logits ----
    {
        const int pair = tid >> 2;            // 0..127 -> (qi, h)
        const int qi = pair >> 3, h = pair & 7;
        const int quarter = tid & 3;
        float* ap = &oa_lds[qi][256 + h * 16 + quarter * 4];
        floatx4 a = *(floatx4*)ap;
        float m = fmaxf(fmaxf(a[0], a[1]), fmaxf(a[2], a[3]));
        m = fmaxf(m, __shfl_xor(m, 1));
        m = fmaxf(m, __shfl_xor(m, 2));
        floatx4 e;
#pragma unroll
        for (int i = 0; i < 4; ++i) e[i] = expf(a[i] - m);
        float s = e[0] + e[1] + e[2] + e[3];
        s += __shfl_xor(s, 1);
        s += __shfl_xor(s, 2);
        const float inv = 1.f / s;
#pragma unroll
        for (int i = 0; i < 4; ++i) e[i] *= inv;
        *(floatx4*)ap = e;
    }
    __syncthreads();

    // ---- sampling: thread (qi, h, sub) -> 8 channels; wv -> LDS ----
    {
        const int pairi = tid >> 2, sub = tid & 3;
        const int qi = pairi >> 3, h = pairi & 7;
        float acc[8];
#pragma unroll
        for (int j = 0; j < 8; ++j) acc[j] = 0.f;
        // head-plane: value[h][b*S + s][32]
        const short* vbase = value + (long)h * BS_ * 32 + (long)b * S_ * 32 + sub * 8;

        for (int l = 0; l < 4; ++l) {
            const int Hl = shp_lds[l][0], Wl = shp_lds[l][1];
            const int st = st_lds[l];
            const float px = pri_lds[qi][l][0], py = pri_lds[qi][l][1];
            const float invW = 1.f / (float)Wl, invH = 1.f / (float)Hl;

            float wgt[16];
            int   off[16];
#pragma unroll
            for (int p = 0; p < 4; ++p) {
                const int cb = h * 16 + l * 4 + p;
                const float ox = oa_lds[qi][cb * 2], oy = oa_lds[qi][cb * 2 + 1];
                const float lx = px + ox * invW, ly = py + oy * invH;
                const float ix = lx * (float)Wl - 0.5f, iy = ly * (float)Hl - 0.5f;
                const float x0f = floorf(ix), y0f = floorf(iy);
                const int x0 = (int)x0f, y0 = (int)y0f;
                const float fx = ix - x0f, fy = iy - y0f;
                const float awv = oa_lds[qi][256 + cb];
#pragma unroll
                for (int dy = 0; dy < 2; ++dy) {
                    const int yc = y0 + dy;
                    const float wy = dy ? fy : 1.f - fy;
                    const int yi = min(max(yc, 0), Hl - 1);
#pragma unroll
                    for (int dx = 0; dx < 2; ++dx) {
                        const int xc = x0 + dx;
                        const float wx = dx ? fx : 1.f - fx;
                        const int xi = min(max(xc, 0), Wl - 1);
                        const bool v = (xc >= 0) & (xc < Wl) & (yc >= 0) & (yc < Hl);
                        const int j = p * 4 + dy * 2 + dx;
                        wgt[j] = v ? wy * wx * awv : 0.f;
                        off[j] = yi * Wl + xi;
                    }
                }
            }
            const short* base = vbase + (long)st * 32;
            short8 vv[16];
#pragma unroll
            for (int j = 0; j < 16; ++j)
                vv[j] = *(const short8*)(base + (long)off[j] * 32);
#pragma unroll
            for (int j = 0; j < 16; ++j) {
                const float w = wgt[j];
#pragma unroll
                for (int c = 0; c < 8; ++c) acc[c] += w * bf2f((unsigned short)vv[j][c]);
            }
        }

        short8 ov;
#pragma unroll
        for (int j = 0; j < 8; ++j) ov[j] = (short)f2bf(acc[j]);
        const int chunk = (h * 4 + sub) ^ (qi & 7);       // XOR swizzle
        *(short8*)&wv_lds[qi][chunk * 8] = ov;
    }
    __syncthreads();

    // ---- out GEMM: wave w -> cols w*32 .. +31 (16 reg-operand MFMAs) ----
    {
        const int lane = tid & 63, w = tid >> 6;
        const int l16 = lane & 15, lq = lane >> 4;

        short8 bfrag[8][2];
#pragma unroll
        for (int kc = 0; kc < 8; ++kc)
#pragma unroll
            for (int nf = 0; nf < 2; ++nf)
                bfrag[kc][nf] = *(const short8*)(
                    Wof + (long)((kc * 16 + w * 2 + nf) * 64 + lane) * 8);

        short8 af[8];
#pragma unroll
        for (int kc = 0; kc < 8; ++kc) {
            const int chunk = (kc * 4 + lq) ^ (l16 & 7);
            af[kc] = *(const short8*)&wv_lds[l16][chunk * 8];
        }

        floatx4 acc2[2];
#pragma unroll
        for (int nf = 0; nf < 2; ++nf) acc2[nf] = (floatx4){0.f, 0.f, 0.f, 0.f};
#pragma unroll
        for (int kc = 0; kc < 8; ++kc)
#pragma unroll
            for (int nf = 0; nf < 2; ++nf)
                acc2[nf] = __builtin_amdgcn_mfma_f32_16x16x32_bf16(
                    bfrag[kc][nf], af[kc], acc2[nf], 0, 0, 0);  // swapped -> row-major

        float* co = out + ((long)b * Qn_ + q0 + l16) * 256 + w * 32 + lq * 4;
#pragma unroll
        for (int nf = 0; nf < 2; ++nf) {
            const floatx4 bv4 = *(const floatx4*)(b_out + w * 32 + nf * 16 + lq * 4);
            *(floatx4*)(co + nf * 16) = acc2[nf] + bv4;
        }
    }
}

// ---------------------------------------------------------------------------
extern "C" void kernel_launch(void* const* d_in, const int* in_sizes, int n_in,
                              void* d_out, int out_size, void* d_ws, size_t ws_size,
                              hipStream_t stream) {
    const float* in_feats = (const float*)d_in[0];
    const float* priors   = (const float*)d_in[1];
    const float* sfeats   = (const float*)d_in[2];
    const int*   shapes   = (const int*)d_in[3];
    const int*   starts   = (const int*)d_in[4];
    const float* W_off    = (const float*)d_in[5];
    const float* b_off    = (const float*)d_in[6];
    const float* W_attn   = (const float*)d_in[7];
    const float* b_attn   = (const float*)d_in[8];
    const float* W_val    = (const float*)d_in[9];
    const float* b_val    = (const float*)d_in[10];
    const float* W_out    = (const float*)d_in[11];
    const float* b_out    = (const float*)d_in[12];
    float* out = (float*)d_out;

    // Workspace: Wvt 128K | Wof 128K | Wcat 192K | value 44.56M (short)
    //            offattn(bf16) 6.29M (short) | bcat 1.5K (f32)
    short* Wvt     = (short*)d_ws;
    short* Wof     = Wvt + 65536;
    short* Wcat    = Wof + 65536;
    short* value   = Wcat + 98304;
    short* offattn = value + (long)BS_ * 256;
    float* bcat    = (float*)(offattn + (long)B_ * Qn_ * 384);

    // all weight prep in one dispatch
    prep_all<<<320, 1024, 0, stream>>>(W_val, W_out, W_off, W_attn, b_off, b_attn,
                                       Wvt, Wcat, Wof, bcat);
    // value GEMM (head-plane out) + offattn GEMM (bf16 out) fused
    gemm_mega<<<256 + (B_ * S_) / 64, 256, 0, stream>>>(
        sfeats, in_feats, Wvt, Wcat, b_val, bcat, value, offattn);
    // softmax + deformable sampling (head-plane value) + out GEMM fused
    sampler_out<<<B_ * (Qn_ / 16), 512, 0, stream>>>(
        priors, shapes, starts, offattn, value, Wof, b_out, out);
}